// Round 1
// baseline (155183.069 us; speedup 1.0000x reference)
//
#include <hip/hip_runtime.h>
#include <hip/hip_bf16.h>

#define NSLAB 64

// ---------------- direct 5x5x5 conv, fp32 ----------------
// grid: (ceil(outD^3/256), Cout, B); block 256. One thread per output element.
__global__ __launch_bounds__(256) void conv5(
    const float* __restrict__ x, const float* __restrict__ W,
    float* __restrict__ y, int Cin, int inD, int outD, int stride)
{
    const int outD3 = outD * outD * outD;
    const size_t inD3 = (size_t)inD * inD * inD;
    int s = blockIdx.x * 256 + threadIdx.x;
    bool active = s < outD3;
    if (!active) s = 0;
    int ow = s % outD; int t = s / outD; int oh = t % outD; int od = t / outD;
    const int co = blockIdx.y, b = blockIdx.z, Cout = gridDim.y;
    const int id0 = od * stride - 4, ih0 = oh * stride - 4, iw0 = ow * stride - 4;
    const float* xb = x + (size_t)b * Cin * inD3;
    const float* wb = W + (size_t)co * Cin * 125;
    float acc = 0.f;
    bool interior = (id0 >= 0) & (id0 + 4 < inD) & (ih0 >= 0) & (ih0 + 4 < inD)
                  & (iw0 >= 0) & (iw0 + 4 < inD);
    if (interior) {
        const float* xo = xb + ((size_t)id0 * inD + ih0) * inD + iw0;
        for (int ci = 0; ci < Cin; ++ci) {
            const float* xc = xo + (size_t)ci * inD3;
            const float* wc = wb + ci * 125;
            #pragma unroll
            for (int kd = 0; kd < 5; ++kd)
                #pragma unroll
                for (int kh = 0; kh < 5; ++kh)
                    #pragma unroll
                    for (int kw = 0; kw < 5; ++kw)
                        acc = fmaf(xc[((size_t)kd * inD + kh) * inD + kw],
                                   wc[(kd * 5 + kh) * 5 + kw], acc);
        }
    } else {
        for (int ci = 0; ci < Cin; ++ci) {
            const float* xc = xb + (size_t)ci * inD3;
            const float* wc = wb + ci * 125;
            #pragma unroll
            for (int kd = 0; kd < 5; ++kd) {
                int id = id0 + kd;
                if ((unsigned)id >= (unsigned)inD) continue;
                #pragma unroll
                for (int kh = 0; kh < 5; ++kh) {
                    int ih = ih0 + kh;
                    if ((unsigned)ih >= (unsigned)inD) continue;
                    #pragma unroll
                    for (int kw = 0; kw < 5; ++kw) {
                        int iw = iw0 + kw;
                        float xv = ((unsigned)iw < (unsigned)inD)
                                 ? xc[((size_t)id * inD + ih) * inD + iw] : 0.f;
                        acc = fmaf(xv, wc[(kd * 5 + kh) * 5 + kw], acc);
                    }
                }
            }
        }
    }
    if (active) y[((size_t)b * Cout + co) * outD3 + s] = acc;
}

// ---------------- BN statistics: partial sums (deterministic, no atomics) ----
// grid: (C, NSLAB); block 256
__global__ __launch_bounds__(256) void bn_partial(
    const float* __restrict__ y, float* __restrict__ part, int B, int C, int S)
{
    const int c = blockIdx.x, slab = blockIdx.y;
    const long total = (long)B * S;
    float sum = 0.f, sq = 0.f;
    for (long i = (long)slab * 256 + threadIdx.x; i < total; i += (long)NSLAB * 256) {
        int b = (int)(i / S); int sp = (int)(i % S);
        float v = y[((size_t)b * C + c) * S + sp];
        sum += v; sq = fmaf(v, v, sq);
    }
    __shared__ float ls[256], lq[256];
    ls[threadIdx.x] = sum; lq[threadIdx.x] = sq; __syncthreads();
    for (int o = 128; o > 0; o >>= 1) {
        if (threadIdx.x < o) { ls[threadIdx.x] += ls[threadIdx.x + o];
                               lq[threadIdx.x] += lq[threadIdx.x + o]; }
        __syncthreads();
    }
    if (threadIdx.x == 0) {
        part[(c * NSLAB + slab) * 2]     = ls[0];
        part[(c * NSLAB + slab) * 2 + 1] = lq[0];
    }
}

__global__ void bn_finalize(const float* __restrict__ part, float* __restrict__ stats,
                            int C, float invN)
{
    int c = blockIdx.x * blockDim.x + threadIdx.x;
    if (c >= C) return;
    float sum = 0.f, sq = 0.f;
    for (int k = 0; k < NSLAB; ++k) {
        sum += part[(c * NSLAB + k) * 2];
        sq  += part[(c * NSLAB + k) * 2 + 1];
    }
    float mean = sum * invN;
    float var  = sq * invN - mean * mean;
    stats[2 * c]     = mean;
    stats[2 * c + 1] = rsqrtf(var + 1e-5f);
}

// ---------------- normalize + relu / gated activation ----------------
// one thread per output (B, d, S) element
__global__ __launch_bounds__(256) void act(
    const float* __restrict__ y, const float* __restrict__ stats,
    float* __restrict__ h, int B, int C, int d, int m0, int m1, int S)
{
    size_t idx = (size_t)blockIdx.x * 256 + threadIdx.x;
    size_t total = (size_t)B * d * S;
    if (idx >= total) return;
    int sp = (int)(idx % S); size_t t = idx / S;
    int c = (int)(t % d); int b = (int)(t / d);
    float v = (y[((size_t)b * C + c) * S + sp] - stats[2 * c]) * stats[2 * c + 1];
    float o;
    if (c < m0) {
        o = fmaxf(v, 0.f);
    } else {
        int gi = (c < m0 + 3 * m1) ? (d + (c - m0) / 3)
                                   : (d + m1 + (c - m0 - 3 * m1) / 5);
        float g = (y[((size_t)b * C + gi) * S + sp] - stats[2 * gi]) * stats[2 * gi + 1];
        o = v / (1.f + __expf(-g));
    }
    h[((size_t)b * d + c) * S + sp] = o;
}

// ---------------- stage 8: fused normalize + relu + spatial mean -------------
// grid (512, B); block 256
__global__ __launch_bounds__(256) void pool_relu(
    const float* __restrict__ y, const float* __restrict__ stats,
    float* __restrict__ pooled, int S)
{
    const int c = blockIdx.x, b = blockIdx.y, C = gridDim.x;
    const float mean = stats[2 * c], inv = stats[2 * c + 1];
    const float* yp = y + ((size_t)b * C + c) * S;
    float sum = 0.f;
    for (int sp = threadIdx.x; sp < S; sp += 256)
        sum += fmaxf((yp[sp] - mean) * inv, 0.f);
    __shared__ float ls[256];
    ls[threadIdx.x] = sum; __syncthreads();
    for (int o = 128; o > 0; o >>= 1) {
        if (threadIdx.x < o) ls[threadIdx.x] += ls[threadIdx.x + o];
        __syncthreads();
    }
    if (threadIdx.x == 0) pooled[(size_t)b * C + c] = ls[0] / (float)S;
}

// ---------------- final linear: [16,512] @ [20,512]^T + b ----------------
// grid (20, 16); block 64 (one wave per output scalar)
__global__ void linear20(const float* __restrict__ pooled, const float* __restrict__ lw,
                         const float* __restrict__ lb, float* __restrict__ out)
{
    const int n = blockIdx.x, b = blockIdx.y;
    const float* p = pooled + b * 512;
    const float* w = lw + n * 512;
    float s = 0.f;
    for (int c = threadIdx.x; c < 512; c += 64) s = fmaf(p[c], w[c], s);
    for (int o = 32; o > 0; o >>= 1) s += __shfl_down(s, o);
    if (threadIdx.x == 0) out[b * 20 + n] = s + lb[n];
}

// ---------------- host side ----------------
struct StageCfg { int cin, cout, d, m0, m1, m2, inD, outD, stride; };

extern "C" void kernel_launch(void* const* d_in, const int* in_sizes, int n_in,
                              void* d_out, int out_size, void* d_ws, size_t ws_size,
                              hipStream_t stream) {
    const float* x = (const float*)d_in[0];
    const float* Ws[8];
    for (int i = 0; i < 8; ++i) Ws[i] = (const float*)d_in[1 + i];
    const float* linW = (const float*)d_in[9];
    const float* linb = (const float*)d_in[10];
    float* out = (float*)d_out;
    float* ws = (float*)d_ws;

    // spatial: 64 ->34 ->38 ->21 ->25 ->15 ->19 ->12 ->16
    static const StageCfg st[8] = {
        {  7,  24,  20,   6,  3, 1, 64, 34, 2},
        { 20,  24,  20,   6,  3, 1, 34, 38, 1},
        { 20,  56,  47,  14,  6, 3, 38, 21, 2},
        { 47,  56,  47,  14,  6, 3, 21, 25, 1},
        { 47, 114,  96,  30, 12, 6, 25, 15, 2},
        { 96, 114,  96,  30, 12, 6, 15, 19, 1},
        { 96, 144, 120,  32, 16, 8, 19, 12, 2},
        {120, 512, 512, 512,  0, 0, 12, 16, 1},
    };
    const int B = 16;

    // workspace layout (floats)
    const size_t Y_ELems = 33554432;        // max y: stage8 16*512*4096
    const size_t H_ELems = 17559040;        // max h: stage2 16*20*38^3
    const size_t OFF_Y = 0;
    const size_t OFF_HA = OFF_Y + Y_ELems;
    const size_t OFF_HB = OFF_HA + H_ELems;
    const size_t OFF_PART = OFF_HB + H_ELems;          // 512*64*2
    const size_t OFF_STATS = OFF_PART + 512 * NSLAB * 2; // 1024
    const size_t OFF_POOL = OFF_STATS + 1024;            // 8192
    const size_t NEED = (OFF_POOL + 8192) * sizeof(float);
    if (ws_size < NEED) return;  // refuse to corrupt memory

    float* yb     = ws + OFF_Y;
    float* hbuf[2] = { ws + OFF_HA, ws + OFF_HB };
    float* part   = ws + OFF_PART;
    float* stats  = ws + OFF_STATS;
    float* pooled = ws + OFF_POOL;

    const float* cur = x;
    for (int i = 0; i < 8; ++i) {
        const StageCfg& s = st[i];
        const int outD3 = s.outD * s.outD * s.outD;

        dim3 gc((outD3 + 255) / 256, s.cout, B);
        conv5<<<gc, 256, 0, stream>>>(cur, Ws[i], yb, s.cin, s.inD, s.outD, s.stride);

        dim3 gp(s.cout, NSLAB);
        bn_partial<<<gp, 256, 0, stream>>>(yb, part, B, s.cout, outD3);
        bn_finalize<<<dim3((s.cout + 255) / 256), 256, 0, stream>>>(
            part, stats, s.cout, 1.f / ((float)B * (float)outD3));

        if (i < 7) {
            size_t tot = (size_t)B * s.d * outD3;
            act<<<dim3((unsigned)((tot + 255) / 256)), 256, 0, stream>>>(
                yb, stats, hbuf[i & 1], B, s.cout, s.d, s.m0, s.m1, outD3);
            cur = hbuf[i & 1];
        } else {
            pool_relu<<<dim3(512, B), 256, 0, stream>>>(yb, stats, pooled, outD3);
            linear20<<<dim3(20, B), 64, 0, stream>>>(pooled, linW, linb, out);
        }
    }
}

// Round 2
// 5685.660 us; speedup vs baseline: 27.2938x; 27.2938x over previous
//
#include <hip/hip_runtime.h>
#include <hip/hip_bf16.h>

typedef __bf16 bf16x8 __attribute__((ext_vector_type(8)));
typedef float f32x4 __attribute__((ext_vector_type(4)));
typedef unsigned int uint4v __attribute__((ext_vector_type(4)));
typedef unsigned short ushortT;

__device__ __forceinline__ ushortT f2b(float f) {
    __bf16 b = (__bf16)f;
    return __builtin_bit_cast(ushortT, b);
}

// ---------------- weight pre-pack: [k8_global][NPAD][8] bf16 ----------------
__global__ void pack_w(const float* __restrict__ W, ushortT* __restrict__ wp,
                       int Cin, int CINP, int Cout, int NPAD, int total)
{
    int e = blockIdx.x * 256 + threadIdx.x;
    if (e >= total) return;
    int j = e & 7;
    int rest = e >> 3;
    int n = rest % NPAD;
    int k8g = rest / NPAD;
    int k = k8g * 8 + j;
    int tap = k / CINP;
    int ci = k - tap * CINP;
    float v = 0.f;
    if (tap < 125 && ci < Cin && n < Cout)
        v = W[((size_t)n * Cin + ci) * 125 + tap];
    wp[e] = f2b(v);
}

// ---------------- input pack: fp32 [16][7][64^3] -> bf16 [16][64^3][8] -------
__global__ void pack_x(const float* __restrict__ x, ushortT* __restrict__ xb)
{
    long e = (long)blockIdx.x * 256 + threadIdx.x;   // 16*262144*8 total
    int j = (int)(e & 7);
    long rest = e >> 3;
    int sp = (int)(rest & 262143);
    int b = (int)(rest >> 18);
    float v = (j < 7) ? x[((size_t)b * 7 + j) * 262144 + sp] : 0.f;
    xb[e] = f2b(v);
}

// ---------------- implicit-GEMM conv via MFMA bf16 ----------------
// A: activations channel-last bf16 [16][IND^3][CINP]; B: packed weights.
// Block: 256 thr = 4 waves; tile M=64 x N=64; wave w owns cols w*16..w*16+15.
template<int CINP, int IND, int OUTD, int STRIDE, int COUT, int NPAD>
__global__ __launch_bounds__(256)
void conv_gemm(const ushortT* __restrict__ xcl, const ushortT* __restrict__ wp,
               float* __restrict__ y)
{
    constexpr int S = OUTD * OUTD * OUTD;
    constexpr long MTOT = 16L * S;
    constexpr int KTOT = 125 * CINP;
    constexpr int KSTEPS = (KTOT + 31) / 32;
    constexpr long IND3 = (long)IND * IND * IND;

    __shared__ ushortT As[64 * 32];
    __shared__ ushortT Bs[64 * 32];

    const int t = threadIdx.x;
    const int lane = t & 63;
    const int wave = t >> 6;
    const long mbase = (long)blockIdx.x * 64;

    // staging identity: this thread stages A row sm, 16B-slot sk8 (and same for B row)
    const int sm = t & 63;
    const int sk8 = t >> 6;                       // 0..3
    long m = mbase + sm; if (m >= MTOT) m = MTOT - 1;
    const int b  = (int)(m / S);
    const int sp = (int)(m % S);
    const int od = sp / (OUTD * OUTD);
    const int oh = (sp / OUTD) % OUTD;
    const int ow = sp % OUTD;
    const int id0 = od * STRIDE - 4, ih0 = oh * STRIDE - 4, iw0 = ow * STRIDE - 4;
    const ushortT* xb = xcl + (size_t)b * IND3 * CINP;

    const ushortT* wsrc = wp + ((size_t)sk8 * NPAD + (size_t)blockIdx.y * 64 + sm) * 8;
    const size_t wstep = (size_t)4 * NPAD * 8;

    // XOR-swizzled LDS offsets (16B slots): row*4 + (slot ^ (row&3))
    const int aoff = (sm * 4 + (sk8 ^ (sm & 3))) * 8;

    int aro[4];
    #pragma unroll
    for (int i = 0; i < 4; ++i) {
        int r = i * 16 + (lane & 15);
        aro[i] = (r * 4 + ((lane >> 4) ^ (r & 3))) * 8;
    }
    const int brn = wave * 16 + (lane & 15);
    const int bro = (brn * 4 + ((lane >> 4) ^ (brn & 3))) * 8;

    f32x4 acc0 = (f32x4)0.f, acc1 = (f32x4)0.f, acc2 = (f32x4)0.f, acc3 = (f32x4)0.f;

    for (int s = 0; s < KSTEPS; ++s) {
        const int k = s * 32 + sk8 * 8;
        const int tap = k / CINP;          // compile-time-const divisor -> magic mul
        const int ci  = k - tap * CINP;
        const int kd = tap / 25;
        const int r25 = tap - kd * 25;
        const int kh = r25 / 5;
        const int kw = r25 - kh * 5;
        const int id = id0 + kd, ih = ih0 + kh, iw = iw0 + kw;
        const bool ok = (tap < 125) & ((unsigned)id < (unsigned)IND)
                      & ((unsigned)ih < (unsigned)IND) & ((unsigned)iw < (unsigned)IND);
        uint4v av = (uint4v)0u;
        if (ok) {
            long xo = (((long)id * IND + ih) * IND + iw) * CINP + ci;
            av = *(const uint4v*)(xb + xo);
        }
        uint4v bvv = *(const uint4v*)(wsrc + (size_t)s * wstep);
        __syncthreads();                              // prior iter's frag reads done
        *(uint4v*)&As[aoff] = av;
        *(uint4v*)&Bs[aoff] = bvv;
        __syncthreads();
        bf16x8 bfr = *(const bf16x8*)&Bs[bro];
        bf16x8 a0 = *(const bf16x8*)&As[aro[0]];
        bf16x8 a1 = *(const bf16x8*)&As[aro[1]];
        bf16x8 a2 = *(const bf16x8*)&As[aro[2]];
        bf16x8 a3 = *(const bf16x8*)&As[aro[3]];
        acc0 = __builtin_amdgcn_mfma_f32_16x16x32_bf16(a0, bfr, acc0, 0, 0, 0);
        acc1 = __builtin_amdgcn_mfma_f32_16x16x32_bf16(a1, bfr, acc1, 0, 0, 0);
        acc2 = __builtin_amdgcn_mfma_f32_16x16x32_bf16(a2, bfr, acc2, 0, 0, 0);
        acc3 = __builtin_amdgcn_mfma_f32_16x16x32_bf16(a3, bfr, acc3, 0, 0, 0);
    }

    // epilogue: D lane map col = lane&15, row = (lane>>4)*4 + reg
    const int nn = (int)blockIdx.y * 64 + wave * 16 + (lane & 15);
    if (nn < COUT) {
        const int rbase = (lane >> 4) * 4;
        f32x4 accs[4] = {acc0, acc1, acc2, acc3};
        #pragma unroll
        for (int i = 0; i < 4; ++i) {
            #pragma unroll
            for (int r = 0; r < 4; ++r) {
                long mm = mbase + i * 16 + rbase + r;
                if (mm < MTOT) y[(size_t)mm * COUT + nn] = accs[i][r];
            }
        }
    }
}

// ---------------- BN partial sums, channel-last y [rows][C] ----------------
// grid 256 blocks; CR = pow2 >= min(C,256); threads with same (t & CR-1) share c.
__global__ __launch_bounds__(256)
void bn_partial_cl(const float* __restrict__ y, float* __restrict__ part,
                   long rows, int C, int crlog2)
{
    const int t = threadIdx.x;
    const int CR = 1 << crlog2;
    const int c = t & (CR - 1);
    const int r0 = t >> crlog2;
    const int rstep = 256 >> crlog2;
    float s0 = 0, q0 = 0, s1 = 0, q1 = 0;
    const bool has0 = c < C, has1 = c + 256 < C;
    for (long r = (long)blockIdx.x * rstep + r0; r < rows; r += 256L * rstep) {
        const float* row = y + (size_t)r * C;
        if (has0) { float v = row[c];       s0 += v; q0 = fmaf(v, v, q0); }
        if (has1) { float v = row[c + 256]; s1 += v; q1 = fmaf(v, v, q1); }
    }
    __shared__ float l0[256], l1[256], l2[256], l3[256];
    l0[t] = s0; l1[t] = q0; l2[t] = s1; l3[t] = q1;
    __syncthreads();
    if (t < CR) {
        for (int j = 1; j < rstep; ++j) {
            s0 += l0[t + j * CR]; q0 += l1[t + j * CR];
            s1 += l2[t + j * CR]; q1 += l3[t + j * CR];
        }
        if (t < C) {
            part[((size_t)blockIdx.x * 512 + t) * 2]     = s0;
            part[((size_t)blockIdx.x * 512 + t) * 2 + 1] = q0;
        }
        if (t + 256 < C) {
            part[((size_t)blockIdx.x * 512 + t + 256) * 2]     = s1;
            part[((size_t)blockIdx.x * 512 + t + 256) * 2 + 1] = q1;
        }
    }
}

__global__ void bn_finalize(const float* __restrict__ part, float* __restrict__ stats,
                            int C, float invN)
{
    int c = blockIdx.x * 256 + threadIdx.x;
    if (c >= C) return;
    float s = 0, q = 0;
    for (int k = 0; k < 256; ++k) {
        s += part[((size_t)k * 512 + c) * 2];
        q += part[((size_t)k * 512 + c) * 2 + 1];
    }
    float mean = s * invN;
    float var = q * invN - mean * mean;
    stats[2 * c] = mean;
    stats[2 * c + 1] = rsqrtf(var + 1e-5f);
}

// ---------------- normalize + gate, write channel-last bf16 [rows][CP] -------
template<int CP>
__global__ __launch_bounds__(256)
void act_cl(const float* __restrict__ y, const float* __restrict__ stats,
            ushortT* __restrict__ h, long rows, int C, int d, int m0, int m1)
{
    long idx = (long)blockIdx.x * 256 + threadIdx.x;
    if (idx >= rows * CP) return;
    int c = (int)(idx % CP);
    long row = idx / CP;
    float o = 0.f;
    if (c < d) {
        float v = (y[(size_t)row * C + c] - stats[2 * c]) * stats[2 * c + 1];
        if (c < m0) {
            o = fmaxf(v, 0.f);
        } else {
            int gi = (c < m0 + 3 * m1) ? (d + (c - m0) / 3)
                                       : (d + m1 + (c - m0 - 3 * m1) / 5);
            float g = (y[(size_t)row * C + gi] - stats[2 * gi]) * stats[2 * gi + 1];
            o = v / (1.f + expf(-g));
        }
    }
    h[(size_t)row * CP + c] = f2b(o);
}

// ---------------- stage-8 pooled relu: y [16][4096][512] ----------------
__global__ __launch_bounds__(256)
void pool_partial(const float* __restrict__ y, const float* __restrict__ stats,
                  float* __restrict__ pp)
{
    const int b = blockIdx.x, slab = blockIdx.y, t = threadIdx.x;
    const int c0 = t, c1 = t + 256;
    const float mu0 = stats[2 * c0], iv0 = stats[2 * c0 + 1];
    const float mu1 = stats[2 * c1], iv1 = stats[2 * c1 + 1];
    float a0 = 0, a1 = 0;
    for (int i = 0; i < 64; ++i) {
        const float* row = y + ((size_t)b * 4096 + slab * 64 + i) * 512;
        a0 += fmaxf((row[c0] - mu0) * iv0, 0.f);
        a1 += fmaxf((row[c1] - mu1) * iv1, 0.f);
    }
    pp[(size_t)(b * 64 + slab) * 512 + c0] = a0;
    pp[(size_t)(b * 64 + slab) * 512 + c1] = a1;
}

__global__ void pool_final(const float* __restrict__ pp, float* __restrict__ pooled)
{
    const int b = blockIdx.x, t = threadIdx.x;
    float a0 = 0, a1 = 0;
    for (int s = 0; s < 64; ++s) {
        a0 += pp[(size_t)(b * 64 + s) * 512 + t];
        a1 += pp[(size_t)(b * 64 + s) * 512 + t + 256];
    }
    pooled[b * 512 + t]       = a0 * (1.f / 4096.f);
    pooled[b * 512 + t + 256] = a1 * (1.f / 4096.f);
}

// ---------------- final linear ----------------
__global__ void linear20(const float* __restrict__ pooled, const float* __restrict__ lw,
                         const float* __restrict__ lb, float* __restrict__ out)
{
    const int n = blockIdx.x, b = blockIdx.y;
    const float* p = pooled + b * 512;
    const float* w = lw + n * 512;
    float s = 0.f;
    for (int c = threadIdx.x; c < 512; c += 64) s = fmaf(p[c], w[c], s);
    for (int o = 32; o > 0; o >>= 1) s += __shfl_down(s, o);
    if (threadIdx.x == 0) out[b * 20 + n] = s + lb[n];
}

// ---------------- host ----------------
extern "C" void kernel_launch(void* const* d_in, const int* in_sizes, int n_in,
                              void* d_out, int out_size, void* d_ws, size_t ws_size,
                              hipStream_t stream) {
    const float* x = (const float*)d_in[0];
    const float* Wf[8];
    for (int i = 0; i < 8; ++i) Wf[i] = (const float*)d_in[1 + i];
    const float* linW = (const float*)d_in[9];
    const float* linb = (const float*)d_in[10];
    float* out = (float*)d_out;
    float* ws = (float*)d_ws;

    // float-offsets into workspace
    const size_t OFF_Y = 0;                 // 33,554,432 f  (fp32 y, stride Cout)
    const size_t OFF_XB = 33554432;         // 16,777,216 f  (bf16 x; reused as hB)
    const size_t OFF_HA = 50331648;         //  7,546,368 f  (bf16 hA)
    const size_t OFF_WP = 57878016;         //  6,564,864 f  (packed weights bf16)
    const size_t OFF_PART = 64442880;       //    262,144 f
    const size_t OFF_PP = 64705024;         //    524,288 f
    const size_t OFF_ST = 65229312;         //      1,024 f
    const size_t OFF_PL = 65230336;         //      8,192 f
    const size_t NEEDF = 65238528;
    if (ws_size < NEEDF * sizeof(float)) return;

    float* yb = ws + OFF_Y;
    ushortT* xb16 = (ushortT*)(ws + OFF_XB);
    ushortT* hA = (ushortT*)(ws + OFF_HA);
    ushortT* hB = (ushortT*)(ws + OFF_XB);  // alias: x dead after stage 1
    ushortT* wpb = (ushortT*)(ws + OFF_WP);
    float* part = ws + OFF_PART;
    float* pp = ws + OFF_PP;
    float* stats = ws + OFF_ST;
    float* pooled = ws + OFF_PL;

    // packed-weight sub-offsets (ushort units) and pack params
    static const size_t wpo[8] = {0, 65536, 258048, 450560, 835584, 1605632, 3141632, 5445632};
    static const int pCin[8]  = {7, 20, 20, 47, 47, 96, 96, 120};
    static const int pCinp[8] = {8, 24, 24, 48, 48, 96, 96, 120};
    static const int pCout[8] = {24, 24, 56, 56, 114, 114, 144, 512};
    static const int pNpad[8] = {64, 64, 64, 64, 128, 128, 192, 512};
    static const int pTot[8]  = {65536, 192512, 192512, 385024, 770048, 1536000, 2304000, 7684096};

    pack_x<<<131072, 256, 0, stream>>>(x, xb16);
    for (int i = 0; i < 8; ++i)
        pack_w<<<(pTot[i] + 255) / 256, 256, 0, stream>>>(
            Wf[i], wpb + wpo[i], pCin[i], pCinp[i], pCout[i], pNpad[i], pTot[i]);

    // per-stage: conv_gemm -> bn_partial -> bn_finalize -> act (or pool+linear)
    long rows;

    // stage 1: CINP 8, 64->34 s2, Cout 24
    rows = 628864;
    conv_gemm<8, 64, 34, 2, 24, 64><<<dim3(9826, 1), 256, 0, stream>>>(xb16, wpb + wpo[0], yb);
    bn_partial_cl<<<256, 256, 0, stream>>>(yb, part, rows, 24, 5);
    bn_finalize<<<1, 256, 0, stream>>>(part, stats, 24, 1.f / (float)rows);
    act_cl<24><<<(unsigned)((rows * 24 + 255) / 256), 256, 0, stream>>>(yb, stats, hA, rows, 24, 20, 6, 3);

    // stage 2: CINP 24, 34->38 s1, Cout 24
    rows = 877952;
    conv_gemm<24, 34, 38, 1, 24, 64><<<dim3(13718, 1), 256, 0, stream>>>(hA, wpb + wpo[1], yb);
    bn_partial_cl<<<256, 256, 0, stream>>>(yb, part, rows, 24, 5);
    bn_finalize<<<1, 256, 0, stream>>>(part, stats, 24, 1.f / (float)rows);
    act_cl<24><<<(unsigned)((rows * 24 + 255) / 256), 256, 0, stream>>>(yb, stats, hB, rows, 24, 20, 6, 3);

    // stage 3: CINP 24, 38->21 s2, Cout 56
    rows = 148176;
    conv_gemm<24, 38, 21, 2, 56, 64><<<dim3(2316, 1), 256, 0, stream>>>(hB, wpb + wpo[2], yb);
    bn_partial_cl<<<256, 256, 0, stream>>>(yb, part, rows, 56, 6);
    bn_finalize<<<1, 256, 0, stream>>>(part, stats, 56, 1.f / (float)rows);
    act_cl<48><<<(unsigned)((rows * 48 + 255) / 256), 256, 0, stream>>>(yb, stats, hA, rows, 56, 47, 14, 6);

    // stage 4: CINP 48, 21->25 s1, Cout 56
    rows = 250000;
    conv_gemm<48, 21, 25, 1, 56, 64><<<dim3(3907, 1), 256, 0, stream>>>(hA, wpb + wpo[3], yb);
    bn_partial_cl<<<256, 256, 0, stream>>>(yb, part, rows, 56, 6);
    bn_finalize<<<1, 256, 0, stream>>>(part, stats, 56, 1.f / (float)rows);
    act_cl<48><<<(unsigned)((rows * 48 + 255) / 256), 256, 0, stream>>>(yb, stats, hB, rows, 56, 47, 14, 6);

    // stage 5: CINP 48, 25->15 s2, Cout 114
    rows = 54000;
    conv_gemm<48, 25, 15, 2, 114, 128><<<dim3(844, 2), 256, 0, stream>>>(hB, wpb + wpo[4], yb);
    bn_partial_cl<<<256, 256, 0, stream>>>(yb, part, rows, 114, 7);
    bn_finalize<<<1, 256, 0, stream>>>(part, stats, 114, 1.f / (float)rows);
    act_cl<96><<<(unsigned)((rows * 96 + 255) / 256), 256, 0, stream>>>(yb, stats, hA, rows, 114, 96, 30, 12);

    // stage 6: CINP 96, 15->19 s1, Cout 114
    rows = 109744;
    conv_gemm<96, 15, 19, 1, 114, 128><<<dim3(1715, 2), 256, 0, stream>>>(hA, wpb + wpo[5], yb);
    bn_partial_cl<<<256, 256, 0, stream>>>(yb, part, rows, 114, 7);
    bn_finalize<<<1, 256, 0, stream>>>(part, stats, 114, 1.f / (float)rows);
    act_cl<96><<<(unsigned)((rows * 96 + 255) / 256), 256, 0, stream>>>(yb, stats, hB, rows, 114, 96, 30, 12);

    // stage 7: CINP 96, 19->12 s2, Cout 144
    rows = 27648;
    conv_gemm<96, 19, 12, 2, 144, 192><<<dim3(432, 3), 256, 0, stream>>>(hB, wpb + wpo[6], yb);
    bn_partial_cl<<<256, 256, 0, stream>>>(yb, part, rows, 144, 8);
    bn_finalize<<<1, 256, 0, stream>>>(part, stats, 144, 1.f / (float)rows);
    act_cl<120><<<(unsigned)((rows * 120 + 255) / 256), 256, 0, stream>>>(yb, stats, hA, rows, 144, 120, 32, 16);

    // stage 8: CINP 120, 12->16 s1, Cout 512; then pool + linear
    rows = 65536;
    conv_gemm<120, 12, 16, 1, 512, 512><<<dim3(1024, 8), 256, 0, stream>>>(hA, wpb + wpo[7], yb);
    bn_partial_cl<<<256, 256, 0, stream>>>(yb, part, rows, 512, 8);
    bn_finalize<<<2, 256, 0, stream>>>(part, stats, 512, 1.f / (float)rows);
    pool_partial<<<dim3(16, 64), 256, 0, stream>>>(yb, stats, pp);
    pool_final<<<16, 256, 0, stream>>>(pp, pooled);
    linear20<<<dim3(20, 16), 64, 0, stream>>>(pooled, linW, linb, out);
}

// Round 3
// 5497.889 us; speedup vs baseline: 28.2259x; 1.0342x over previous
//
#include <hip/hip_runtime.h>
#include <hip/hip_bf16.h>

typedef __bf16 bf16x8 __attribute__((ext_vector_type(8)));
typedef float f32x4 __attribute__((ext_vector_type(4)));
typedef unsigned int uint4v __attribute__((ext_vector_type(4)));
typedef unsigned short ushortT;
typedef ushortT ushort8v __attribute__((ext_vector_type(8)));

__device__ __forceinline__ ushortT f2b(float f) {
    __bf16 b = (__bf16)f;
    return __builtin_bit_cast(ushortT, b);
}

// ---------------- input pack: fp32 [16][7][64^3] -> halo-padded bf16 ----------
// layout [16][72][72][72][8], halo = 4 each side, zeros outside + pad channel 7
__global__ __launch_bounds__(256) void pack_x(const float* __restrict__ x,
                                              ushortT* __restrict__ xb)
{
    long e = (long)blockIdx.x * 256 + threadIdx.x;   // 16*72^3 = 5,971,968
    if (e >= 5971968L) return;
    int wp_ = (int)(e % 72); long r = e / 72;
    int hp = (int)(r % 72); r /= 72;
    int dp = (int)(r % 72); int b = (int)(r / 72);
    ushort8v v = (ushort8v)0;
    int dd = dp - 4, hh = hp - 4, ww = wp_ - 4;
    if ((unsigned)dd < 64u && (unsigned)hh < 64u && (unsigned)ww < 64u) {
        int sp = (dd * 64 + hh) * 64 + ww;
        #pragma unroll
        for (int c = 0; c < 7; ++c)
            v[c] = f2b(x[((size_t)(b * 7 + c)) * 262144 + sp]);
    }
    *(ushort8v*)(xb + e * 8) = v;
}

// ---------------- weight pack: [NBY][KSTEPS][4 slots][NW][8] bf16 -------------
__global__ void pack_w(const float* __restrict__ W, ushortT* __restrict__ wp,
                       int Cin, int CINP, int Cout, int NW, int KSTEPS, int total)
{
    int e = blockIdx.x * 256 + threadIdx.x;
    if (e >= total) return;
    int j = e & 7;
    int r = e >> 3;
    int c = r % NW; r /= NW;
    int q = r & 3; r >>= 2;
    int s = r % KSTEPS;
    int nby = r / KSTEPS;
    int k = s * 32 + q * 8 + j;
    int tap = k / CINP;
    int ci = k - tap * CINP;
    int n = nby * NW + c;
    float v = 0.f;
    if (tap < 125 && ci < Cin && n < Cout)
        v = W[((size_t)n * Cin + ci) * 125 + tap];
    wp[e] = f2b(v);
}

// ---------------- implicit-GEMM conv, no LDS, A+B direct to registers --------
// block 256 = 4 waves; block tile M=256 (wave: 64 rows), N = NW = NFRAG*16.
template<int CINP, int INDP, int OUTD, int STRIDE, int COUT, int NFRAG, int KSTEPS, int KTOT>
__global__ __launch_bounds__(256)
void conv_ig(const ushortT* __restrict__ xcl, const ushortT* __restrict__ wp,
             float* __restrict__ y)
{
    constexpr int S3 = OUTD * OUTD * OUTD;
    constexpr long MTOT = 16L * S3;
    constexpr int NW = NFRAG * 16;
    const int t = threadIdx.x, lane = t & 63, wave = t >> 6;
    const long mbase = (long)blockIdx.x * 256 + wave * 64;
    const int slot = lane >> 4;

    // affine row bases (halo-padded coords: padded = od*STRIDE + kd, kd in 0..4)
    unsigned rb[4];
    #pragma unroll
    for (int i = 0; i < 4; ++i) {
        long m = mbase + i * 16 + (lane & 15);
        if (m >= MTOT) m = MTOT - 1;
        int b = (int)(m / S3); int sp = (int)(m % S3);
        int od = sp / (OUTD * OUTD); int oh = (sp / OUTD) % OUTD; int ow = sp % OUTD;
        rb[i] = (unsigned)(((((b * INDP) + od * STRIDE) * INDP + oh * STRIDE) * INDP
                            + ow * STRIDE) * CINP);
    }
    const ushortT* wptr = wp + ((size_t)((blockIdx.y * KSTEPS) * 4 + slot) * NW
                                + (lane & 15)) * 8;

    f32x4 acc[NFRAG][4];
    #pragma unroll
    for (int n = 0; n < NFRAG; ++n)
        #pragma unroll
        for (int i = 0; i < 4; ++i) acc[n][i] = (f32x4)0.f;

    for (int s = 0; s < KSTEPS; ++s) {
        const int k0 = s * 32 + slot * 8;
        const int tap = k0 / CINP;            // compile-time divisor -> magic mul
        const int ci = k0 - tap * CINP;
        const int kd = tap / 25;
        const int rr = tap - kd * 25;
        const int kh = rr / 5;
        const int kw = rr - kh * 5;
        const unsigned toff = (unsigned)(((kd * INDP + kh) * INDP + kw) * CINP + ci);
        const bool valid = k0 < KTOT;         // K tail -> read halo zeros at idx 0
        uint4v a[4];
        #pragma unroll
        for (int i = 0; i < 4; ++i) {
            unsigned idx = valid ? (rb[i] + toff) : 0u;
            a[i] = *(const uint4v*)(xcl + idx);
        }
        uint4v bv[NFRAG];
        #pragma unroll
        for (int n = 0; n < NFRAG; ++n)
            bv[n] = *(const uint4v*)(wptr + (size_t)s * (4 * NW * 8) + n * 128);
        #pragma unroll
        for (int n = 0; n < NFRAG; ++n) {
            bf16x8 bb = __builtin_bit_cast(bf16x8, bv[n]);
            #pragma unroll
            for (int i = 0; i < 4; ++i)
                acc[n][i] = __builtin_amdgcn_mfma_f32_16x16x32_bf16(
                    __builtin_bit_cast(bf16x8, a[i]), bb, acc[n][i], 0, 0, 0);
        }
    }

    // epilogue: C/D map col = lane&15, row = (lane>>4)*4 + reg
    const int rbase = (lane >> 4) * 4;
    #pragma unroll
    for (int n = 0; n < NFRAG; ++n) {
        int nn = blockIdx.y * NW + n * 16 + (lane & 15);
        if (nn >= COUT) continue;
        #pragma unroll
        for (int i = 0; i < 4; ++i) {
            #pragma unroll
            for (int r = 0; r < 4; ++r) {
                long mm = mbase + i * 16 + rbase + r;
                if (mm < MTOT) y[(size_t)mm * COUT + nn] = acc[n][i][r];
            }
        }
    }
}

// ---------------- BN partial sums over y [rows][C], C<=256 ----------------
__global__ __launch_bounds__(256)
void bn_partial_cl(const float* __restrict__ y, float* __restrict__ part,
                   long rows, int C, int crlog2)
{
    const int t = threadIdx.x;
    const int CR = 1 << crlog2;
    const int c = t & (CR - 1);
    const int r0 = t >> crlog2;
    const int rstep = 256 >> crlog2;
    float s0 = 0.f, q0 = 0.f;
    const bool has = c < C;
    for (long r = (long)blockIdx.x * rstep + r0; r < rows; r += 256L * rstep) {
        if (has) { float v = y[(size_t)r * C + c]; s0 += v; q0 = fmaf(v, v, q0); }
    }
    __shared__ float l0[256], l1[256];
    l0[t] = s0; l1[t] = q0; __syncthreads();
    if (t < CR) {
        for (int j = 1; j < rstep; ++j) { s0 += l0[t + j * CR]; q0 += l1[t + j * CR]; }
        if (t < C) {
            part[((size_t)blockIdx.x * 256 + t) * 2]     = s0;
            part[((size_t)blockIdx.x * 256 + t) * 2 + 1] = q0;
        }
    }
}

__global__ void bn_finalize(const float* __restrict__ part, float* __restrict__ stats,
                            int C, float invN)
{
    int c = threadIdx.x;
    if (c >= C) return;
    float s = 0.f, q = 0.f;
    for (int k = 0; k < 256; ++k) {
        s += part[((size_t)k * 256 + c) * 2];
        q += part[((size_t)k * 256 + c) * 2 + 1];
    }
    float mean = s * invN;
    float var = q * invN - mean * mean;
    stats[2 * c] = mean;
    stats[2 * c + 1] = rsqrtf(var + 1e-5f);
}

// ---------------- normalize + gate -> halo-padded bf16 for next stage --------
template<int CINP, int INDP, int OUTD>
__global__ __launch_bounds__(256)
void act_pad(const float* __restrict__ y, const float* __restrict__ stats,
             ushortT* __restrict__ h, int COUT, int d, int m0, int m1)
{
    constexpr long TOT = 16L * INDP * INDP * INDP * CINP;
    long e = (long)blockIdx.x * 256 + threadIdx.x;
    if (e >= TOT) return;
    int c = (int)(e % CINP); long r = e / CINP;
    int wp_ = (int)(r % INDP); r /= INDP;
    int hp = (int)(r % INDP); r /= INDP;
    int dp = (int)(r % INDP); int b = (int)(r / INDP);
    float o = 0.f;
    int dd = dp - 4, hh = hp - 4, ww = wp_ - 4;
    if (c < d && (unsigned)dd < (unsigned)OUTD && (unsigned)hh < (unsigned)OUTD
        && (unsigned)ww < (unsigned)OUTD) {
        long row = ((b * (long)OUTD + dd) * OUTD + hh) * OUTD + ww;
        float v = (y[row * COUT + c] - stats[2 * c]) * stats[2 * c + 1];
        if (c < m0) {
            o = fmaxf(v, 0.f);
        } else {
            int gi = (c < m0 + 3 * m1) ? (d + (c - m0) / 3)
                                       : (d + m1 + (c - m0 - 3 * m1) / 5);
            float g = (y[row * COUT + gi] - stats[2 * gi]) * stats[2 * gi + 1];
            o = v / (1.f + __expf(-g));
        }
    }
    h[e] = f2b(o);
}

// ---------------- stage-8 pooling (per 256-channel half) ----------------
__global__ __launch_bounds__(256)
void pool_partial(const float* __restrict__ y, const float* __restrict__ stats,
                  float* __restrict__ pp)
{
    const int b = blockIdx.x, slab = blockIdx.y, c = threadIdx.x;
    const float mu = stats[2 * c], iv = stats[2 * c + 1];
    float a = 0.f;
    for (int i = 0; i < 64; ++i)
        a += fmaxf((y[((size_t)b * 4096 + slab * 64 + i) * 256 + c] - mu) * iv, 0.f);
    pp[(size_t)(b * 64 + slab) * 256 + c] = a;
}

__global__ void pool_final(const float* __restrict__ pp, float* __restrict__ pooled)
{
    const int b = blockIdx.x, c = threadIdx.x;
    float a = 0.f;
    for (int s = 0; s < 64; ++s) a += pp[(size_t)(b * 64 + s) * 256 + c];
    pooled[b * 512 + c] = a * (1.f / 4096.f);   // caller offsets pooled by half*256
}

// ---------------- final linear ----------------
__global__ void linear20(const float* __restrict__ pooled, const float* __restrict__ lw,
                         const float* __restrict__ lb, float* __restrict__ out)
{
    const int n = blockIdx.x, b = blockIdx.y;
    const float* p = pooled + b * 512;
    const float* w = lw + n * 512;
    float s = 0.f;
    for (int c = threadIdx.x; c < 512; c += 64) s = fmaf(p[c], w[c], s);
    for (int o = 32; o > 0; o >>= 1) s += __shfl_down(s, o);
    if (threadIdx.x == 0) out[b * 20 + n] = s + lb[n];
}

// ---------------- host ----------------
extern "C" void kernel_launch(void* const* d_in, const int* in_sizes, int n_in,
                              void* d_out, int out_size, void* d_ws, size_t ws_size,
                              hipStream_t stream) {
    const float* x = (const float*)d_in[0];
    const float* Wf[8];
    for (int i = 0; i < 8; ++i) Wf[i] = (const float*)d_in[1 + i];
    const float* linW = (const float*)d_in[9];
    const float* linb = (const float*)d_in[10];
    float* out = (float*)d_out;
    float* ws = (float*)d_ws;

    // workspace layout (float units)
    const size_t OFF_Y   = 0;                    // 21,070,848 f (max y: s2)
    const size_t OFF_H   = 21070848;             // 23,887,872 f (bf16, max: padded x)
    const size_t OFF_WP  = 44958720;             //  6,212,352 f (packed weights bf16)
    const size_t OFF_PART= 51171072;             //    131,072 f
    const size_t OFF_PP  = 51302144;             //    262,144 f
    const size_t OFF_ST  = 51564288;             //      1,024 f
    const size_t OFF_PL  = 51565312;             //      8,192 f
    const size_t NEEDF   = 51573504;             // ~206.3 MB
    if (ws_size < NEEDF * sizeof(float)) return;

    float* yb = ws + OFF_Y;
    ushortT* H = (ushortT*)(ws + OFF_H);
    ushortT* wpb = (ushortT*)(ws + OFF_WP);
    float* part = ws + OFF_PART;
    float* pp = ws + OFF_PP;
    float* stats = ws + OFF_ST;
    float* pooled = ws + OFF_PL;

    // packed-weight offsets (ushort units): sizes NBY*KSTEPS*4*NW*8
    static const size_t wpo[8] = {0, 32768, 129024, 321536, 706560, 1476608, 3012608, 4740608};
    static const int pCin[8]   = {7, 20, 20, 47, 47, 96, 96, 120};
    static const int pCinp[8]  = {8, 24, 24, 48, 48, 96, 96, 120};
    static const int pCout[8]  = {24, 24, 56, 56, 114, 114, 144, 512};
    static const int pNW[8]    = {32, 32, 64, 64, 64, 64, 48, 64};
    static const int pKst[8]   = {32, 94, 94, 188, 188, 375, 375, 469};
    static const int pTot[8]   = {32768, 96256, 192512, 385024, 770048, 1536000, 1728000, 7684096};

    pack_x<<<23328, 256, 0, stream>>>(x, H);
    for (int i = 0; i < 8; ++i)
        pack_w<<<(pTot[i] + 255) / 256, 256, 0, stream>>>(
            Wf[i], wpb + wpo[i], pCin[i], pCinp[i], pCout[i], pNW[i], pKst[i], pTot[i]);

    long rows;

    // stage 1: 64->34 s2, Cout 24, K=1000
    rows = 628864;
    conv_ig<8, 72, 34, 2, 24, 2, 32, 1000><<<dim3(2457, 1), 256, 0, stream>>>(H, wpb + wpo[0], yb);
    bn_partial_cl<<<256, 256, 0, stream>>>(yb, part, rows, 24, 5);
    bn_finalize<<<1, 256, 0, stream>>>(part, stats, 24, 1.f / (float)rows);
    act_pad<24, 42, 34><<<111132, 256, 0, stream>>>(yb, stats, H, 24, 20, 6, 3);

    // stage 2: 34->38 s1, Cout 24, K=3000
    rows = 877952;
    conv_ig<24, 42, 38, 1, 24, 2, 94, 3000><<<dim3(3430, 1), 256, 0, stream>>>(H, wpb + wpo[1], yb);
    bn_partial_cl<<<256, 256, 0, stream>>>(yb, part, rows, 24, 5);
    bn_finalize<<<1, 256, 0, stream>>>(part, stats, 24, 1.f / (float)rows);
    act_pad<24, 46, 38><<<146004, 256, 0, stream>>>(yb, stats, H, 24, 20, 6, 3);

    // stage 3: 38->21 s2, Cout 56, K=3000
    rows = 148176;
    conv_ig<24, 46, 21, 2, 56, 4, 94, 3000><<<dim3(579, 1), 256, 0, stream>>>(H, wpb + wpo[2], yb);
    bn_partial_cl<<<256, 256, 0, stream>>>(yb, part, rows, 56, 6);
    bn_finalize<<<1, 256, 0, stream>>>(part, stats, 56, 1.f / (float)rows);
    act_pad<48, 29, 21><<<73167, 256, 0, stream>>>(yb, stats, H, 56, 47, 14, 6);

    // stage 4: 21->25 s1, Cout 56, K=6000
    rows = 250000;
    conv_ig<48, 29, 25, 1, 56, 4, 188, 6000><<<dim3(977, 1), 256, 0, stream>>>(H, wpb + wpo[3], yb);
    bn_partial_cl<<<256, 256, 0, stream>>>(yb, part, rows, 56, 6);
    bn_finalize<<<1, 256, 0, stream>>>(part, stats, 56, 1.f / (float)rows);
    act_pad<48, 33, 25><<<107811, 256, 0, stream>>>(yb, stats, H, 56, 47, 14, 6);

    // stage 5: 25->15 s2, Cout 114, K=6000
    rows = 54000;
    conv_ig<48, 33, 15, 2, 114, 4, 188, 6000><<<dim3(211, 2), 256, 0, stream>>>(H, wpb + wpo[4], yb);
    bn_partial_cl<<<256, 256, 0, stream>>>(yb, part, rows, 114, 7);
    bn_finalize<<<1, 256, 0, stream>>>(part, stats, 114, 1.f / (float)rows);
    act_pad<96, 23, 15><<<73002, 256, 0, stream>>>(yb, stats, H, 114, 96, 30, 12);

    // stage 6: 15->19 s1, Cout 114, K=12000
    rows = 109744;
    conv_ig<96, 23, 19, 1, 114, 4, 375, 12000><<<dim3(429, 2), 256, 0, stream>>>(H, wpb + wpo[5], yb);
    bn_partial_cl<<<256, 256, 0, stream>>>(yb, part, rows, 114, 7);
    bn_finalize<<<1, 256, 0, stream>>>(part, stats, 114, 1.f / (float)rows);
    act_pad<96, 27, 19><<<118098, 256, 0, stream>>>(yb, stats, H, 114, 96, 30, 12);

    // stage 7: 19->12 s2, Cout 144, K=12000
    rows = 27648;
    conv_ig<96, 27, 12, 2, 144, 3, 375, 12000><<<dim3(108, 3), 256, 0, stream>>>(H, wpb + wpo[6], yb);
    bn_partial_cl<<<256, 256, 0, stream>>>(yb, part, rows, 144, 8);
    bn_finalize<<<1, 256, 0, stream>>>(part, stats, 144, 1.f / (float)rows);
    act_pad<120, 20, 12><<<60000, 256, 0, stream>>>(yb, stats, H, 144, 120, 32, 16);

    // stage 8: 12->16 s1, Cout 512 as two 256-channel halves, K=15000
    rows = 65536;
    for (int h8 = 0; h8 < 2; ++h8) {
        conv_ig<120, 20, 16, 1, 256, 4, 469, 15000><<<dim3(256, 4), 256, 0, stream>>>(
            H, wpb + wpo[7] + (size_t)h8 * 3842048, yb);
        bn_partial_cl<<<256, 256, 0, stream>>>(yb, part, rows, 256, 8);
        bn_finalize<<<1, 256, 0, stream>>>(part, stats, 256, 1.f / (float)rows);
        pool_partial<<<dim3(16, 64), 256, 0, stream>>>(yb, stats, pp);
        pool_final<<<16, 256, 0, stream>>>(pp, pooled + h8 * 256);
    }
    linear20<<<dim3(20, 16), 64, 0, stream>>>(pooled, linW, linb, out);
}

// Round 5
// 4245.279 us; speedup vs baseline: 36.5543x; 1.2951x over previous
//
#include <hip/hip_runtime.h>
#include <hip/hip_bf16.h>

typedef __bf16 bf16x8 __attribute__((ext_vector_type(8)));
typedef float f32x4 __attribute__((ext_vector_type(4)));
typedef unsigned int uint4v __attribute__((ext_vector_type(4)));
typedef unsigned short ushortT;
typedef ushortT ushort8v __attribute__((ext_vector_type(8)));

__device__ __forceinline__ ushortT f2b(float f) {
    __bf16 b = (__bf16)f;
    return __builtin_bit_cast(ushortT, b);
}

// bijective chunked XCD swizzle (m204)
__device__ __forceinline__ unsigned xcd_swz(unsigned bx, unsigned nwg) {
    unsigned q = nwg >> 3, r = nwg & 7, xcd = bx & 7, off = bx >> 3;
    return (xcd < r ? xcd * (q + 1) : r * (q + 1) + (xcd - r) * q) + off;
}

// ---------------- input pack: fp32 [16][7][64^3] -> halo-padded bf16 ----------
__global__ __launch_bounds__(256) void pack_x(const float* __restrict__ x,
                                              ushortT* __restrict__ xb)
{
    long e = (long)blockIdx.x * 256 + threadIdx.x;   // 16*72^3 = 5,971,968
    if (e >= 5971968L) return;
    int wp_ = (int)(e % 72); long r = e / 72;
    int hp = (int)(r % 72); r /= 72;
    int dp = (int)(r % 72); int b = (int)(r / 72);
    ushort8v v = (ushort8v)0;
    int dd = dp - 4, hh = hp - 4, ww = wp_ - 4;
    if ((unsigned)dd < 64u && (unsigned)hh < 64u && (unsigned)ww < 64u) {
        int sp = (dd * 64 + hh) * 64 + ww;
        #pragma unroll
        for (int c = 0; c < 7; ++c)
            v[c] = f2b(x[((size_t)(b * 7 + c)) * 262144 + sp]);
    }
    *(ushort8v*)(xb + e * 8) = v;
}

// ---------------- weight pack (conv_ig layout): [NBY][KSTEPS][4][NW][8] -------
__global__ void pack_w(const float* __restrict__ W, ushortT* __restrict__ wp,
                       int Cin, int CINP, int Cout, int NW, int KSTEPS, int total)
{
    int e = blockIdx.x * 256 + threadIdx.x;
    if (e >= total) return;
    int j = e & 7;
    int r = e >> 3;
    int c = r % NW; r /= NW;
    int q = r & 3; r >>= 2;
    int s = r % KSTEPS;
    int nby = r / KSTEPS;
    int k = s * 32 + q * 8 + j;
    int tap = k / CINP;
    int ci = k - tap * CINP;
    int n = nby * NW + c;
    float v = 0.f;
    if (tap < 125 && ci < Cin && n < Cout)
        v = W[((size_t)n * Cin + ci) * 125 + tap];
    wp[e] = f2b(v);
}

// ------ weight pack (conv_lds layout): [NBY][CHUNKS][63 steps][4 q][NW][8] ----
// k-mapping: tap = 2s + (q>>1); ci = c*16 + (q&1)*8 + j
__global__ void pack_w_lds(const float* __restrict__ W, ushortT* __restrict__ wp,
                           int Cin, int Cout, int NW, int CHUNKS, int total)
{
    int e = blockIdx.x * 256 + threadIdx.x;
    if (e >= total) return;
    int j = e & 7;
    int r = e >> 3;
    int n = r % NW; r /= NW;
    int q = r & 3; r >>= 2;
    int s = r % 63; r /= 63;
    int c = r % CHUNKS;
    int nby = r / CHUNKS;
    int tap = 2 * s + (q >> 1);
    int ci = c * 16 + (q & 1) * 8 + j;
    int nn = nby * NW + n;
    float v = 0.f;
    if (tap < 125 && ci < Cin && nn < Cout)
        v = W[((size_t)nn * Cin + ci) * 125 + tap];
    wp[e] = f2b(v);
}

// ---------------- implicit-GEMM conv, direct global A ----------------
template<int CINP, int INDP, int OUTD, int STRIDE, int COUT, int NFRAG, int KSTEPS, int KTOT>
__global__ __launch_bounds__(256)
void conv_ig(const ushortT* __restrict__ xcl, const ushortT* __restrict__ wp,
             float* __restrict__ y)
{
    constexpr int S3 = OUTD * OUTD * OUTD;
    constexpr long MTOT = 16L * S3;
    constexpr int NW = NFRAG * 16;
    const int t = threadIdx.x, lane = t & 63, wave = t >> 6;
    const unsigned bx = xcd_swz(blockIdx.x, gridDim.x);
    const long mbase = (long)bx * 256 + wave * 64;
    const int slot = lane >> 4;

    unsigned rb[4];
    #pragma unroll
    for (int i = 0; i < 4; ++i) {
        long m = mbase + i * 16 + (lane & 15);
        if (m >= MTOT) m = MTOT - 1;
        int b = (int)(m / S3); int sp = (int)(m % S3);
        int od = sp / (OUTD * OUTD); int oh = (sp / OUTD) % OUTD; int ow = sp % OUTD;
        rb[i] = (unsigned)(((((b * INDP) + od * STRIDE) * INDP + oh * STRIDE) * INDP
                            + ow * STRIDE) * CINP);
    }
    const ushortT* wptr = wp + ((size_t)((blockIdx.y * KSTEPS) * 4 + slot) * NW
                                + (lane & 15)) * 8;

    f32x4 acc[NFRAG][4];
    #pragma unroll
    for (int n = 0; n < NFRAG; ++n)
        #pragma unroll
        for (int i = 0; i < 4; ++i) acc[n][i] = (f32x4)0.f;

    for (int s = 0; s < KSTEPS; ++s) {
        const int k0 = s * 32 + slot * 8;
        const int tap = k0 / CINP;
        const int ci = k0 - tap * CINP;
        const int kd = tap / 25;
        const int rr = tap - kd * 25;
        const int kh = rr / 5;
        const int kw = rr - kh * 5;
        const unsigned toff = (unsigned)(((kd * INDP + kh) * INDP + kw) * CINP + ci);
        const bool valid = k0 < KTOT;
        uint4v a[4];
        #pragma unroll
        for (int i = 0; i < 4; ++i) {
            unsigned idx = valid ? (rb[i] + toff) : 0u;
            a[i] = *(const uint4v*)(xcl + idx);
        }
        uint4v bv[NFRAG];
        #pragma unroll
        for (int n = 0; n < NFRAG; ++n)
            bv[n] = *(const uint4v*)(wptr + (size_t)s * (4 * NW * 8) + n * 128);
        #pragma unroll
        for (int n = 0; n < NFRAG; ++n) {
            bf16x8 bb = __builtin_bit_cast(bf16x8, bv[n]);
            #pragma unroll
            for (int i = 0; i < 4; ++i)
                acc[n][i] = __builtin_amdgcn_mfma_f32_16x16x32_bf16(
                    __builtin_bit_cast(bf16x8, a[i]), bb, acc[n][i], 0, 0, 0);
        }
    }

    const int rbase = (lane >> 4) * 4;
    #pragma unroll
    for (int n = 0; n < NFRAG; ++n) {
        int nn = blockIdx.y * NW + n * 16 + (lane & 15);
        if (nn >= COUT) continue;
        #pragma unroll
        for (int i = 0; i < 4; ++i) {
            #pragma unroll
            for (int r = 0; r < 4; ++r) {
                long mm = mbase + i * 16 + rbase + r;
                if (mm < MTOT) y[(size_t)mm * COUT + nn] = acc[n][i][r];
            }
        }
    }
}

// ---------------- LDS-patch implicit-GEMM conv (BISECT: stage 8 only) --------
template<int CHUNKS, int INDP, int OUTD, int TD, int TH, int COUT, int NFRAG>
__global__ __launch_bounds__(256)
void conv_lds(const ushortT* __restrict__ xcl, const ushortT* __restrict__ wp,
              float* __restrict__ y)
{
    constexpr int CH = CHUNKS * 16;
    constexpr int PD = TD + 4, PH = TH + 4, PW = INDP;
    constexpr int P3 = PD * PH * PW;
    constexpr int ROWS = TD * TH * OUTD;
    constexpr int NW = NFRAG * 16;
    constexpr int NTD = (OUTD + TD - 1) / TD;
    constexpr int NTH = (OUTD + TH - 1) / TH;
    constexpr size_t PERNBY = (size_t)CHUNKS * 63 * 4 * NW * 8;

    __shared__ __align__(16) ushortT patch[P3 * 16];
    __shared__ int tofftab[128];

    const int t = threadIdx.x, lane = t & 63, wave = t >> 6;
    const unsigned bt = xcd_swz(blockIdx.x, gridDim.x);
    const int img = bt / (NTD * NTH);
    const int t2 = bt % (NTD * NTH);
    const int od0 = (t2 / NTH) * TD;
    const int oh0 = (t2 % NTH) * TH;

    if (t < 128) {
        int tap = t < 125 ? t : 0;
        int kd = tap / 25, rr = tap - kd * 25, kh = rr / 5, kw = rr - kh * 5;
        tofftab[t] = (t < 125) ? ((kd * PH + kh) * PW + kw) : 0;
    }

    const int r16 = lane & 15, q = lane >> 4;
    const int tp = q >> 1, half = q & 1;

    int rb[4];
    #pragma unroll
    for (int i = 0; i < 4; ++i) {
        int r = wave * 64 + i * 16 + r16;
        if (r >= ROWS) r = ROWS - 1;
        int td = r / (TH * OUTD); int rem = r - td * (TH * OUTD);
        int th = rem / OUTD; int ow = rem - th * OUTD;
        rb[i] = (td * PH + th) * PW + ow;
    }

    const ushortT* wb = wp + (size_t)blockIdx.y * PERNBY + ((size_t)q * NW + r16) * 8;
    const ushortT* src0 = xcl + (size_t)img * INDP * INDP * INDP * CH;

    f32x4 acc[NFRAG][4];
    #pragma unroll
    for (int n = 0; n < NFRAG; ++n)
        #pragma unroll
        for (int i = 0; i < 4; ++i) acc[n][i] = (f32x4)0.f;

    for (int c = 0; c < CHUNKS; ++c) {
        __syncthreads();
        for (int u = t; u < P3 * 2; u += 256) {
            int p = u >> 1, hf = u & 1;
            int pd = p / (PH * PW); int pr = p - pd * (PH * PW);
            int ph = pr / PW; int pw = pr - ph * PW;
            int gd = od0 + pd; if (gd > INDP - 1) gd = INDP - 1;
            int gh = oh0 + ph; if (gh > INDP - 1) gh = INDP - 1;
            const ushortT* sp_ = src0 + (((size_t)gd * INDP + gh) * INDP + pw) * CH
                                 + c * 16 + hf * 8;
            uint4v v = *(const uint4v*)sp_;
            int dst = p * 16 + (hf ^ ((p >> 2) & 1)) * 8;
            *(uint4v*)&patch[dst] = v;
        }
        __syncthreads();
        const ushortT* wc = wb + (size_t)c * (63 * 4 * NW * 8);
        for (int s = 0; s < 63; ++s) {
            int toffv = tofftab[2 * s + tp];
            uint4v bv[NFRAG];
            #pragma unroll
            for (int n = 0; n < NFRAG; ++n)
                bv[n] = *(const uint4v*)(wc + (size_t)s * (4 * NW * 8) + n * 128);
            #pragma unroll
            for (int i = 0; i < 4; ++i) {
                int pos = rb[i] + toffv;
                int ad = pos * 16 + (half ^ ((pos >> 2) & 1)) * 8;
                bf16x8 av = *(const bf16x8*)&patch[ad];
                #pragma unroll
                for (int n = 0; n < NFRAG; ++n)
                    acc[n][i] = __builtin_amdgcn_mfma_f32_16x16x32_bf16(
                        av, __builtin_bit_cast(bf16x8, bv[n]), acc[n][i], 0, 0, 0);
            }
        }
    }

    #pragma unroll
    for (int i = 0; i < 4; ++i) {
        #pragma unroll
        for (int vr = 0; vr < 4; ++vr) {
            int r = wave * 64 + i * 16 + q * 4 + vr;
            if (r >= ROWS) continue;
            int td = r / (TH * OUTD); int rem = r - td * (TH * OUTD);
            int th = rem / OUTD; int ow = rem - th * OUTD;
            int od = od0 + td, oh = oh0 + th;
            if (od >= OUTD || oh >= OUTD) continue;
            size_t row = ((size_t)img * OUTD + od) * (size_t)(OUTD * OUTD)
                       + (size_t)oh * OUTD + ow;
            #pragma unroll
            for (int n = 0; n < NFRAG; ++n) {
                int nn = blockIdx.y * NW + n * 16 + r16;
                if (nn < COUT) y[row * COUT + nn] = acc[n][i][vr];
            }
        }
    }
}

// ---------------- BN partial sums over y [rows][C], C<=256 ----------------
__global__ __launch_bounds__(256)
void bn_partial_cl(const float* __restrict__ y, float* __restrict__ part,
                   long rows, int C, int crlog2)
{
    const int t = threadIdx.x;
    const int CR = 1 << crlog2;
    const int c = t & (CR - 1);
    const int r0 = t >> crlog2;
    const int rstep = 256 >> crlog2;
    float s0 = 0.f, q0 = 0.f;
    const bool has = c < C;
    for (long r = (long)blockIdx.x * rstep + r0; r < rows; r += 256L * rstep) {
        if (has) { float v = y[(size_t)r * C + c]; s0 += v; q0 = fmaf(v, v, q0); }
    }
    __shared__ float l0[256], l1[256];
    l0[t] = s0; l1[t] = q0; __syncthreads();
    if (t < CR) {
        for (int j = 1; j < rstep; ++j) { s0 += l0[t + j * CR]; q0 += l1[t + j * CR]; }
        if (t < C) {
            part[((size_t)blockIdx.x * 256 + t) * 2]     = s0;
            part[((size_t)blockIdx.x * 256 + t) * 2 + 1] = q0;
        }
    }
}

__global__ void bn_finalize(const float* __restrict__ part, float* __restrict__ stats,
                            int C, float invN)
{
    int c = threadIdx.x;
    if (c >= C) return;
    float s = 0.f, q = 0.f;
    for (int k = 0; k < 256; ++k) {
        s += part[((size_t)k * 256 + c) * 2];
        q += part[((size_t)k * 256 + c) * 2 + 1];
    }
    float mean = s * invN;
    float var = q * invN - mean * mean;
    stats[2 * c] = mean;
    stats[2 * c + 1] = rsqrtf(var + 1e-5f);
}

// ---------------- normalize + gate -> halo-padded bf16 for next stage --------
template<int CINP, int INDP, int OUTD>
__global__ __launch_bounds__(256)
void act_pad(const float* __restrict__ y, const float* __restrict__ stats,
             ushortT* __restrict__ h, int COUT, int d, int m0, int m1)
{
    constexpr long TOT = 16L * INDP * INDP * INDP * CINP;
    long e = (long)blockIdx.x * 256 + threadIdx.x;
    if (e >= TOT) return;
    int c = (int)(e % CINP); long r = e / CINP;
    int wp_ = (int)(r % INDP); r /= INDP;
    int hp = (int)(r % INDP); r /= INDP;
    int dp = (int)(r % INDP); int b = (int)(r / INDP);
    float o = 0.f;
    int dd = dp - 4, hh = hp - 4, ww = wp_ - 4;
    if (c < d && (unsigned)dd < (unsigned)OUTD && (unsigned)hh < (unsigned)OUTD
        && (unsigned)ww < (unsigned)OUTD) {
        long row = ((b * (long)OUTD + dd) * OUTD + hh) * OUTD + ww;
        float v = (y[row * COUT + c] - stats[2 * c]) * stats[2 * c + 1];
        if (c < m0) {
            o = fmaxf(v, 0.f);
        } else {
            int gi = (c < m0 + 3 * m1) ? (d + (c - m0) / 3)
                                       : (d + m1 + (c - m0 - 3 * m1) / 5);
            float g = (y[row * COUT + gi] - stats[2 * gi]) * stats[2 * gi + 1];
            o = v / (1.f + __expf(-g));
        }
    }
    h[e] = f2b(o);
}

// ---------------- stage-8 pooling (per 256-channel half) ----------------
__global__ __launch_bounds__(256)
void pool_partial(const float* __restrict__ y, const float* __restrict__ stats,
                  float* __restrict__ pp)
{
    const int b = blockIdx.x, slab = blockIdx.y, c = threadIdx.x;
    const float mu = stats[2 * c], iv = stats[2 * c + 1];
    float a = 0.f;
    for (int i = 0; i < 64; ++i)
        a += fmaxf((y[((size_t)b * 4096 + slab * 64 + i) * 256 + c] - mu) * iv, 0.f);
    pp[(size_t)(b * 64 + slab) * 256 + c] = a;
}

__global__ void pool_final(const float* __restrict__ pp, float* __restrict__ pooled)
{
    const int b = blockIdx.x, c = threadIdx.x;
    float a = 0.f;
    for (int s = 0; s < 64; ++s) a += pp[(size_t)(b * 64 + s) * 256 + c];
    pooled[b * 512 + c] = a * (1.f / 4096.f);
}

// ---------------- final linear ----------------
__global__ void linear20(const float* __restrict__ pooled, const float* __restrict__ lw,
                         const float* __restrict__ lb, float* __restrict__ out)
{
    const int n = blockIdx.x, b = blockIdx.y;
    const float* p = pooled + b * 512;
    const float* w = lw + n * 512;
    float s = 0.f;
    for (int c = threadIdx.x; c < 512; c += 64) s = fmaf(p[c], w[c], s);
    for (int o = 32; o > 0; o >>= 1) s += __shfl_down(s, o);
    if (threadIdx.x == 0) out[b * 20 + n] = s + lb[n];
}

// ---------------- host ----------------
extern "C" void kernel_launch(void* const* d_in, const int* in_sizes, int n_in,
                              void* d_out, int out_size, void* d_ws, size_t ws_size,
                              hipStream_t stream) {
    const float* x = (const float*)d_in[0];
    const float* Wf[8];
    for (int i = 0; i < 8; ++i) Wf[i] = (const float*)d_in[1 + i];
    const float* linW = (const float*)d_in[9];
    const float* linb = (const float*)d_in[10];
    float* out = (float*)d_out;
    float* ws = (float*)d_ws;

    // workspace layout (float units)
    const size_t OFF_Y    = 0;            // 21,070,848 f
    const size_t OFF_H    = 21070848;     // 23,887,872 f (bf16)
    const size_t OFF_WP   = 44958720;     //  6,499,072 f (bf16)
    const size_t OFF_PART = 51457792;     //    131,072 f
    const size_t OFF_PP   = 51588864;     //    262,144 f
    const size_t OFF_ST   = 51851008;     //      1,024 f
    const size_t OFF_PL   = 51852032;     //      8,192 f
    const size_t NEEDF    = 51860224;     // ~207.4 MB
    if (ws_size < NEEDF * sizeof(float)) return;

    float* yb = ws + OFF_Y;
    ushortT* H = (ushortT*)(ws + OFF_H);
    ushortT* wpb = (ushortT*)(ws + OFF_WP);
    float* part = ws + OFF_PART;
    float* pp = ws + OFF_PP;
    float* stats = ws + OFF_ST;
    float* pooled = ws + OFF_PL;

    // packed-weight offsets (ushort units)
    const size_t WPO_S1 = 0;          // ig: 32*4*32*8        = 32,768
    const size_t WPO_S2 = 32768;      // ig: 94*4*32*8        = 96,256
    const size_t WPO_S3 = 129024;     // ig: 94*4*64*8        = 192,512
    const size_t WPO_S4 = 321536;     // ig: 188*4*64*8       = 385,024
    const size_t WPO_S5 = 706560;     // ig: 2*188*4*64*8     = 770,048
    const size_t WPO_S6 = 1476608;    // ig: 2*375*4*64*8     = 1,536,000
    const size_t WPO_S7 = 3012608;    // ig: 3*375*4*48*8     = 1,728,000
    const size_t WPO_S8 = 4740608;    // lds: 8*8*63*4*64*8   = 8,257,536

    pack_x<<<23328, 256, 0, stream>>>(x, H);
    pack_w<<<(32768 + 255) / 256, 256, 0, stream>>>(Wf[0], wpb + WPO_S1, 7, 8, 24, 32, 32, 32768);
    pack_w<<<(96256 + 255) / 256, 256, 0, stream>>>(Wf[1], wpb + WPO_S2, 20, 24, 24, 32, 94, 96256);
    pack_w<<<(192512 + 255) / 256, 256, 0, stream>>>(Wf[2], wpb + WPO_S3, 20, 24, 56, 64, 94, 192512);
    pack_w<<<(385024 + 255) / 256, 256, 0, stream>>>(Wf[3], wpb + WPO_S4, 47, 48, 56, 64, 188, 385024);
    pack_w<<<(770048 + 255) / 256, 256, 0, stream>>>(Wf[4], wpb + WPO_S5, 47, 48, 114, 64, 188, 770048);
    pack_w<<<(1536000 + 255) / 256, 256, 0, stream>>>(Wf[5], wpb + WPO_S6, 96, 96, 114, 64, 375, 1536000);
    pack_w<<<(1728000 + 255) / 256, 256, 0, stream>>>(Wf[6], wpb + WPO_S7, 96, 96, 144, 48, 375, 1728000);
    pack_w_lds<<<(8257536 + 255) / 256, 256, 0, stream>>>(Wf[7], wpb + WPO_S8, 120, 512, 64, 8, 8257536);

    long rows;

    // stage 1 (ig): 64->34 s2, Cout 24, K=1000
    rows = 628864;
    conv_ig<8, 72, 34, 2, 24, 2, 32, 1000><<<dim3(2457, 1), 256, 0, stream>>>(H, wpb + WPO_S1, yb);
    bn_partial_cl<<<256, 256, 0, stream>>>(yb, part, rows, 24, 5);
    bn_finalize<<<1, 256, 0, stream>>>(part, stats, 24, 1.f / (float)rows);
    act_pad<24, 42, 34><<<111132, 256, 0, stream>>>(yb, stats, H, 24, 20, 6, 3);

    // stage 2 (ig): 34->38 s1, Cout 24, K=3000
    rows = 877952;
    conv_ig<24, 42, 38, 1, 24, 2, 94, 3000><<<dim3(3430, 1), 256, 0, stream>>>(H, wpb + WPO_S2, yb);
    bn_partial_cl<<<256, 256, 0, stream>>>(yb, part, rows, 24, 5);
    bn_finalize<<<1, 256, 0, stream>>>(part, stats, 24, 1.f / (float)rows);
    act_pad<24, 46, 38><<<146004, 256, 0, stream>>>(yb, stats, H, 24, 20, 6, 3);

    // stage 3 (ig): 38->21 s2, Cout 56, K=3000
    rows = 148176;
    conv_ig<24, 46, 21, 2, 56, 4, 94, 3000><<<dim3(579, 1), 256, 0, stream>>>(H, wpb + WPO_S3, yb);
    bn_partial_cl<<<256, 256, 0, stream>>>(yb, part, rows, 56, 6);
    bn_finalize<<<1, 256, 0, stream>>>(part, stats, 56, 1.f / (float)rows);
    act_pad<48, 29, 21><<<73167, 256, 0, stream>>>(yb, stats, H, 56, 47, 14, 6);

    // stage 4 (ig): 21->25 s1, Cout 56, K=6000
    rows = 250000;
    conv_ig<48, 29, 25, 1, 56, 4, 188, 6000><<<dim3(977, 1), 256, 0, stream>>>(H, wpb + WPO_S4, yb);
    bn_partial_cl<<<256, 256, 0, stream>>>(yb, part, rows, 56, 6);
    bn_finalize<<<1, 256, 0, stream>>>(part, stats, 56, 1.f / (float)rows);
    act_pad<48, 33, 25><<<107811, 256, 0, stream>>>(yb, stats, H, 56, 47, 14, 6);

    // stage 5 (ig): 25->15 s2, Cout 114, K=6000
    rows = 54000;
    conv_ig<48, 33, 15, 2, 114, 4, 188, 6000><<<dim3(211, 2), 256, 0, stream>>>(H, wpb + WPO_S5, yb);
    bn_partial_cl<<<256, 256, 0, stream>>>(yb, part, rows, 114, 7);
    bn_finalize<<<1, 256, 0, stream>>>(part, stats, 114, 1.f / (float)rows);
    act_pad<96, 23, 15><<<73002, 256, 0, stream>>>(yb, stats, H, 114, 96, 30, 12);

    // stage 6 (ig): 15->19 s1, Cout 114, K=12000
    rows = 109744;
    conv_ig<96, 23, 19, 1, 114, 4, 375, 12000><<<dim3(429, 2), 256, 0, stream>>>(H, wpb + WPO_S6, yb);
    bn_partial_cl<<<256, 256, 0, stream>>>(yb, part, rows, 114, 7);
    bn_finalize<<<1, 256, 0, stream>>>(part, stats, 114, 1.f / (float)rows);
    act_pad<96, 27, 19><<<118098, 256, 0, stream>>>(yb, stats, H, 114, 96, 30, 12);

    // stage 7 (ig): 19->12 s2, Cout 144, K=12000
    rows = 27648;
    conv_ig<96, 27, 12, 2, 144, 3, 375, 12000><<<dim3(108, 3), 256, 0, stream>>>(H, wpb + WPO_S7, yb);
    bn_partial_cl<<<256, 256, 0, stream>>>(yb, part, rows, 144, 8);
    bn_finalize<<<1, 256, 0, stream>>>(part, stats, 144, 1.f / (float)rows);
    act_pad<128, 20, 12><<<64000, 256, 0, stream>>>(yb, stats, H, 144, 120, 32, 16); // pad 120->128ch

    // stage 8 (lds, BISECT): 12->16 s1, Cout 512 as two 256-col halves
    rows = 65536;
    for (int h8 = 0; h8 < 2; ++h8) {
        conv_lds<8, 20, 16, 4, 4, 256, 4><<<dim3(256, 4), 256, 0, stream>>>(
            H, wpb + WPO_S8 + (size_t)h8 * 4128768, yb);
        bn_partial_cl<<<256, 256, 0, stream>>>(yb, part, rows, 256, 8);
        bn_finalize<<<1, 256, 0, stream>>>(part, stats, 256, 1.f / (float)rows);
        pool_partial<<<dim3(16, 64), 256, 0, stream>>>(yb, stats, pp);
        pool_final<<<16, 256, 0, stream>>>(pp, pooled + h8 * 256);
    }
    linear20<<<dim3(20, 16), 64, 0, stream>>>(pooled, linW, linb, out);
}

// Round 6
// 4053.804 us; speedup vs baseline: 38.2809x; 1.0472x over previous
//
#include <hip/hip_runtime.h>
#include <hip/hip_bf16.h>

typedef __bf16 bf16x8 __attribute__((ext_vector_type(8)));
typedef float f32x4 __attribute__((ext_vector_type(4)));
typedef unsigned int uint4v __attribute__((ext_vector_type(4)));
typedef unsigned short ushortT;
typedef ushortT ushort8v __attribute__((ext_vector_type(8)));

__device__ __forceinline__ ushortT f2b(float f) {
    __bf16 b = (__bf16)f;
    return __builtin_bit_cast(ushortT, b);
}

// bijective chunked XCD swizzle (m204)
__device__ __forceinline__ unsigned xcd_swz(unsigned bx, unsigned nwg) {
    unsigned q = nwg >> 3, r = nwg & 7, xcd = bx & 7, off = bx >> 3;
    return (xcd < r ? xcd * (q + 1) : r * (q + 1) + (xcd - r) * q) + off;
}

// ---------------- input pack: fp32 [16][7][64^3] -> halo-padded bf16 ----------
__global__ __launch_bounds__(256) void pack_x(const float* __restrict__ x,
                                              ushortT* __restrict__ xb)
{
    long e = (long)blockIdx.x * 256 + threadIdx.x;   // 16*72^3 = 5,971,968
    if (e >= 5971968L) return;
    int wp_ = (int)(e % 72); long r = e / 72;
    int hp = (int)(r % 72); r /= 72;
    int dp = (int)(r % 72); int b = (int)(r / 72);
    ushort8v v = (ushort8v)0;
    int dd = dp - 4, hh = hp - 4, ww = wp_ - 4;
    if ((unsigned)dd < 64u && (unsigned)hh < 64u && (unsigned)ww < 64u) {
        int sp = (dd * 64 + hh) * 64 + ww;
        #pragma unroll
        for (int c = 0; c < 7; ++c)
            v[c] = f2b(x[((size_t)(b * 7 + c)) * 262144 + sp]);
    }
    *(ushort8v*)(xb + e * 8) = v;
}

// ---------------- weight pack (conv_ig layout): [NBY][KSTEPS][4][NW][8] -------
__global__ void pack_w(const float* __restrict__ W, ushortT* __restrict__ wp,
                       int Cin, int CINP, int Cout, int NW, int KSTEPS, int total)
{
    int e = blockIdx.x * 256 + threadIdx.x;
    if (e >= total) return;
    int j = e & 7;
    int r = e >> 3;
    int c = r % NW; r /= NW;
    int q = r & 3; r >>= 2;
    int s = r % KSTEPS;
    int nby = r / KSTEPS;
    int k = s * 32 + q * 8 + j;
    int tap = k / CINP;
    int ci = k - tap * CINP;
    int n = nby * NW + c;
    float v = 0.f;
    if (tap < 125 && ci < Cin && n < Cout)
        v = W[((size_t)n * Cin + ci) * 125 + tap];
    wp[e] = f2b(v);
}

// ------ weight pack (conv_lds layout): [NBY][CHUNKS][63 steps][4 q][NW][8] ----
// k-mapping: tap = 2s + (q>>1); ci = c*16 + (q&1)*8 + j
__global__ void pack_w_lds(const float* __restrict__ W, ushortT* __restrict__ wp,
                           int Cin, int Cout, int NW, int CHUNKS, int total)
{
    int e = blockIdx.x * 256 + threadIdx.x;
    if (e >= total) return;
    int j = e & 7;
    int r = e >> 3;
    int n = r % NW; r /= NW;
    int q = r & 3; r >>= 2;
    int s = r % 63; r /= 63;
    int c = r % CHUNKS;
    int nby = r / CHUNKS;
    int tap = 2 * s + (q >> 1);
    int ci = c * 16 + (q & 1) * 8 + j;
    int nn = nby * NW + n;
    float v = 0.f;
    if (tap < 125 && ci < Cin && nn < Cout)
        v = W[((size_t)nn * Cin + ci) * 125 + tap];
    wp[e] = f2b(v);
}

// ---------------- implicit-GEMM conv, direct global A ----------------
template<int CINP, int INDP, int OUTD, int STRIDE, int COUT, int NFRAG, int KSTEPS, int KTOT>
__global__ __launch_bounds__(256)
void conv_ig(const ushortT* __restrict__ xcl, const ushortT* __restrict__ wp,
             float* __restrict__ y)
{
    constexpr int S3 = OUTD * OUTD * OUTD;
    constexpr long MTOT = 16L * S3;
    constexpr int NW = NFRAG * 16;
    const int t = threadIdx.x, lane = t & 63, wave = t >> 6;
    const unsigned bx = xcd_swz(blockIdx.x, gridDim.x);
    const long mbase = (long)bx * 256 + wave * 64;
    const int slot = lane >> 4;

    unsigned rb[4];
    #pragma unroll
    for (int i = 0; i < 4; ++i) {
        long m = mbase + i * 16 + (lane & 15);
        if (m >= MTOT) m = MTOT - 1;
        int b = (int)(m / S3); int sp = (int)(m % S3);
        int od = sp / (OUTD * OUTD); int oh = (sp / OUTD) % OUTD; int ow = sp % OUTD;
        rb[i] = (unsigned)(((((b * INDP) + od * STRIDE) * INDP + oh * STRIDE) * INDP
                            + ow * STRIDE) * CINP);
    }
    const ushortT* wptr = wp + ((size_t)((blockIdx.y * KSTEPS) * 4 + slot) * NW
                                + (lane & 15)) * 8;

    f32x4 acc[NFRAG][4];
    #pragma unroll
    for (int n = 0; n < NFRAG; ++n)
        #pragma unroll
        for (int i = 0; i < 4; ++i) acc[n][i] = (f32x4)0.f;

    for (int s = 0; s < KSTEPS; ++s) {
        const int k0 = s * 32 + slot * 8;
        const int tap = k0 / CINP;
        const int ci = k0 - tap * CINP;
        const int kd = tap / 25;
        const int rr = tap - kd * 25;
        const int kh = rr / 5;
        const int kw = rr - kh * 5;
        const unsigned toff = (unsigned)(((kd * INDP + kh) * INDP + kw) * CINP + ci);
        const bool valid = k0 < KTOT;
        uint4v a[4];
        #pragma unroll
        for (int i = 0; i < 4; ++i) {
            unsigned idx = valid ? (rb[i] + toff) : 0u;
            a[i] = *(const uint4v*)(xcl + idx);
        }
        uint4v bv[NFRAG];
        #pragma unroll
        for (int n = 0; n < NFRAG; ++n)
            bv[n] = *(const uint4v*)(wptr + (size_t)s * (4 * NW * 8) + n * 128);
        #pragma unroll
        for (int n = 0; n < NFRAG; ++n) {
            bf16x8 bb = __builtin_bit_cast(bf16x8, bv[n]);
            #pragma unroll
            for (int i = 0; i < 4; ++i)
                acc[n][i] = __builtin_amdgcn_mfma_f32_16x16x32_bf16(
                    __builtin_bit_cast(bf16x8, a[i]), bb, acc[n][i], 0, 0, 0);
        }
    }

    const int rbase = (lane >> 4) * 4;
    #pragma unroll
    for (int n = 0; n < NFRAG; ++n) {
        int nn = blockIdx.y * NW + n * 16 + (lane & 15);
        if (nn >= COUT) continue;
        #pragma unroll
        for (int i = 0; i < 4; ++i) {
            #pragma unroll
            for (int r = 0; r < 4; ++r) {
                long mm = mbase + i * 16 + rbase + r;
                if (mm < MTOT) y[(size_t)mm * COUT + nn] = acc[n][i][r];
            }
        }
    }
}

// ---------------- LDS-patch implicit-GEMM conv (stages 4, 6, 8) --------------
template<int CHUNKS, int INDP, int OUTD, int TD, int TH, int COUT, int NFRAG>
__global__ __launch_bounds__(256)
void conv_lds(const ushortT* __restrict__ xcl, const ushortT* __restrict__ wp,
              float* __restrict__ y)
{
    constexpr int CH = CHUNKS * 16;
    constexpr int PD = TD + 4, PH = TH + 4, PW = INDP;
    constexpr int P3 = PD * PH * PW;
    constexpr int ROWS = TD * TH * OUTD;
    constexpr int NW = NFRAG * 16;
    constexpr int NTD = (OUTD + TD - 1) / TD;
    constexpr int NTH = (OUTD + TH - 1) / TH;
    constexpr size_t PERNBY = (size_t)CHUNKS * 63 * 4 * NW * 8;

    __shared__ __align__(16) ushortT patch[P3 * 16];
    __shared__ int tofftab[128];

    const int t = threadIdx.x, lane = t & 63, wave = t >> 6;
    const unsigned bt = xcd_swz(blockIdx.x, gridDim.x);
    const int img = bt / (NTD * NTH);
    const int t2 = bt % (NTD * NTH);
    const int od0 = (t2 / NTH) * TD;
    const int oh0 = (t2 % NTH) * TH;

    if (t < 128) {
        int tap = t < 125 ? t : 0;
        int kd = tap / 25, rr = tap - kd * 25, kh = rr / 5, kw = rr - kh * 5;
        tofftab[t] = (t < 125) ? ((kd * PH + kh) * PW + kw) : 0;
    }

    const int r16 = lane & 15, q = lane >> 4;
    const int tp = q >> 1, half = q & 1;

    int rb[4];
    #pragma unroll
    for (int i = 0; i < 4; ++i) {
        int r = wave * 64 + i * 16 + r16;
        if (r >= ROWS) r = ROWS - 1;
        int td = r / (TH * OUTD); int rem = r - td * (TH * OUTD);
        int th = rem / OUTD; int ow = rem - th * OUTD;
        rb[i] = (td * PH + th) * PW + ow;
    }

    const ushortT* wb = wp + (size_t)blockIdx.y * PERNBY + ((size_t)q * NW + r16) * 8;
    const ushortT* src0 = xcl + (size_t)img * INDP * INDP * INDP * CH;

    f32x4 acc[NFRAG][4];
    #pragma unroll
    for (int n = 0; n < NFRAG; ++n)
        #pragma unroll
        for (int i = 0; i < 4; ++i) acc[n][i] = (f32x4)0.f;

    for (int c = 0; c < CHUNKS; ++c) {
        __syncthreads();
        for (int u = t; u < P3 * 2; u += 256) {
            int p = u >> 1, hf = u & 1;
            int pd = p / (PH * PW); int pr = p - pd * (PH * PW);
            int ph = pr / PW; int pw = pr - ph * PW;
            int gd = od0 + pd; if (gd > INDP - 1) gd = INDP - 1;
            int gh = oh0 + ph; if (gh > INDP - 1) gh = INDP - 1;
            const ushortT* sp_ = src0 + (((size_t)gd * INDP + gh) * INDP + pw) * CH
                                 + c * 16 + hf * 8;
            uint4v v = *(const uint4v*)sp_;
            int dst = p * 16 + (hf ^ ((p >> 2) & 1)) * 8;
            *(uint4v*)&patch[dst] = v;
        }
        __syncthreads();
        const ushortT* wc = wb + (size_t)c * (63 * 4 * NW * 8);
        for (int s = 0; s < 63; ++s) {
            int toffv = tofftab[2 * s + tp];
            uint4v bv[NFRAG];
            #pragma unroll
            for (int n = 0; n < NFRAG; ++n)
                bv[n] = *(const uint4v*)(wc + (size_t)s * (4 * NW * 8) + n * 128);
            #pragma unroll
            for (int i = 0; i < 4; ++i) {
                int pos = rb[i] + toffv;
                int ad = pos * 16 + (half ^ ((pos >> 2) & 1)) * 8;
                bf16x8 av = *(const bf16x8*)&patch[ad];
                #pragma unroll
                for (int n = 0; n < NFRAG; ++n)
                    acc[n][i] = __builtin_amdgcn_mfma_f32_16x16x32_bf16(
                        av, __builtin_bit_cast(bf16x8, bv[n]), acc[n][i], 0, 0, 0);
            }
        }
    }

    #pragma unroll
    for (int i = 0; i < 4; ++i) {
        #pragma unroll
        for (int vr = 0; vr < 4; ++vr) {
            int r = wave * 64 + i * 16 + q * 4 + vr;
            if (r >= ROWS) continue;
            int td = r / (TH * OUTD); int rem = r - td * (TH * OUTD);
            int th = rem / OUTD; int ow = rem - th * OUTD;
            int od = od0 + td, oh = oh0 + th;
            if (od >= OUTD || oh >= OUTD) continue;
            size_t row = ((size_t)img * OUTD + od) * (size_t)(OUTD * OUTD)
                       + (size_t)oh * OUTD + ow;
            #pragma unroll
            for (int n = 0; n < NFRAG; ++n) {
                int nn = blockIdx.y * NW + n * 16 + r16;
                if (nn < COUT) y[row * COUT + nn] = acc[n][i][vr];
            }
        }
    }
}

// ---------------- BN partial sums over y [rows][C], C<=256 ----------------
__global__ __launch_bounds__(256)
void bn_partial_cl(const float* __restrict__ y, float* __restrict__ part,
                   long rows, int C, int crlog2)
{
    const int t = threadIdx.x;
    const int CR = 1 << crlog2;
    const int c = t & (CR - 1);
    const int r0 = t >> crlog2;
    const int rstep = 256 >> crlog2;
    float s0 = 0.f, q0 = 0.f;
    const bool has = c < C;
    for (long r = (long)blockIdx.x * rstep + r0; r < rows; r += 256L * rstep) {
        if (has) { float v = y[(size_t)r * C + c]; s0 += v; q0 = fmaf(v, v, q0); }
    }
    __shared__ float l0[256], l1[256];
    l0[t] = s0; l1[t] = q0; __syncthreads();
    if (t < CR) {
        for (int j = 1; j < rstep; ++j) { s0 += l0[t + j * CR]; q0 += l1[t + j * CR]; }
        if (t < C) {
            part[((size_t)blockIdx.x * 256 + t) * 2]     = s0;
            part[((size_t)blockIdx.x * 256 + t) * 2 + 1] = q0;
        }
    }
}

__global__ void bn_finalize(const float* __restrict__ part, float* __restrict__ stats,
                            int C, float invN)
{
    int c = threadIdx.x;
    if (c >= C) return;
    float s = 0.f, q = 0.f;
    for (int k = 0; k < 256; ++k) {
        s += part[((size_t)k * 256 + c) * 2];
        q += part[((size_t)k * 256 + c) * 2 + 1];
    }
    float mean = s * invN;
    float var = q * invN - mean * mean;
    stats[2 * c] = mean;
    stats[2 * c + 1] = rsqrtf(var + 1e-5f);
}

// ---------------- normalize + gate -> halo-padded bf16 for next stage --------
template<int CINP, int INDP, int OUTD>
__global__ __launch_bounds__(256)
void act_pad(const float* __restrict__ y, const float* __restrict__ stats,
             ushortT* __restrict__ h, int COUT, int d, int m0, int m1)
{
    constexpr long TOT = 16L * INDP * INDP * INDP * CINP;
    long e = (long)blockIdx.x * 256 + threadIdx.x;
    if (e >= TOT) return;
    int c = (int)(e % CINP); long r = e / CINP;
    int wp_ = (int)(r % INDP); r /= INDP;
    int hp = (int)(r % INDP); r /= INDP;
    int dp = (int)(r % INDP); int b = (int)(r / INDP);
    float o = 0.f;
    int dd = dp - 4, hh = hp - 4, ww = wp_ - 4;
    if (c < d && (unsigned)dd < (unsigned)OUTD && (unsigned)hh < (unsigned)OUTD
        && (unsigned)ww < (unsigned)OUTD) {
        long row = ((b * (long)OUTD + dd) * OUTD + hh) * OUTD + ww;
        float v = (y[row * COUT + c] - stats[2 * c]) * stats[2 * c + 1];
        if (c < m0) {
            o = fmaxf(v, 0.f);
        } else {
            int gi = (c < m0 + 3 * m1) ? (d + (c - m0) / 3)
                                       : (d + m1 + (c - m0 - 3 * m1) / 5);
            float g = (y[row * COUT + gi] - stats[2 * gi]) * stats[2 * gi + 1];
            o = v / (1.f + __expf(-g));
        }
    }
    h[e] = f2b(o);
}

// ---------------- stage-8 pooling (per 256-channel half) ----------------
__global__ __launch_bounds__(256)
void pool_partial(const float* __restrict__ y, const float* __restrict__ stats,
                  float* __restrict__ pp)
{
    const int b = blockIdx.x, slab = blockIdx.y, c = threadIdx.x;
    const float mu = stats[2 * c], iv = stats[2 * c + 1];
    float a = 0.f;
    for (int i = 0; i < 64; ++i)
        a += fmaxf((y[((size_t)b * 4096 + slab * 64 + i) * 256 + c] - mu) * iv, 0.f);
    pp[(size_t)(b * 64 + slab) * 256 + c] = a;
}

__global__ void pool_final(const float* __restrict__ pp, float* __restrict__ pooled)
{
    const int b = blockIdx.x, c = threadIdx.x;
    float a = 0.f;
    for (int s = 0; s < 64; ++s) a += pp[(size_t)(b * 64 + s) * 256 + c];
    pooled[b * 512 + c] = a * (1.f / 4096.f);
}

// ---------------- final linear ----------------
__global__ void linear20(const float* __restrict__ pooled, const float* __restrict__ lw,
                         const float* __restrict__ lb, float* __restrict__ out)
{
    const int n = blockIdx.x, b = blockIdx.y;
    const float* p = pooled + b * 512;
    const float* w = lw + n * 512;
    float s = 0.f;
    for (int c = threadIdx.x; c < 512; c += 64) s = fmaf(p[c], w[c], s);
    for (int o = 32; o > 0; o >>= 1) s += __shfl_down(s, o);
    if (threadIdx.x == 0) out[b * 20 + n] = s + lb[n];
}

// ---------------- host ----------------
extern "C" void kernel_launch(void* const* d_in, const int* in_sizes, int n_in,
                              void* d_out, int out_size, void* d_ws, size_t ws_size,
                              hipStream_t stream) {
    const float* x = (const float*)d_in[0];
    const float* Wf[8];
    for (int i = 0; i < 8; ++i) Wf[i] = (const float*)d_in[1 + i];
    const float* linW = (const float*)d_in[9];
    const float* linb = (const float*)d_in[10];
    float* out = (float*)d_out;
    float* ws = (float*)d_ws;

    // workspace layout (float units)
    const size_t OFF_Y    = 0;            // 21,070,848 f
    const size_t OFF_H    = 21070848;     // 23,887,872 f (bf16)
    const size_t OFF_WP   = 44958720;     //  6,570,752 f (bf16)
    const size_t OFF_PART = 51529472;     //    131,072 f
    const size_t OFF_PP   = 51660544;     //    262,144 f
    const size_t OFF_ST   = 51922688;     //      1,024 f
    const size_t OFF_PL   = 51923712;     //      8,192 f
    const size_t NEEDF    = 51931904;     // ~207.7 MB
    if (ws_size < NEEDF * sizeof(float)) return;

    float* yb = ws + OFF_Y;
    ushortT* H = (ushortT*)(ws + OFF_H);
    ushortT* wpb = (ushortT*)(ws + OFF_WP);
    float* part = ws + OFF_PART;
    float* pp = ws + OFF_PP;
    float* stats = ws + OFF_ST;
    float* pooled = ws + OFF_PL;

    // packed-weight offsets (ushort units)
    const size_t WPO_S1 = 0;          // ig:  32*4*32*8       = 32,768
    const size_t WPO_S2 = 32768;      // ig:  94*4*32*8       = 96,256
    const size_t WPO_S3 = 129024;     // ig:  94*4*64*8       = 192,512
    const size_t WPO_S5 = 321536;     // ig:  2*188*4*64*8    = 770,048
    const size_t WPO_S7 = 1091584;    // ig:  3*375*4*48*8    = 1,728,000
    const size_t WPO_S4 = 2819584;    // lds: 1*4*63*4*64*8   = 516,096
    const size_t WPO_S6 = 3335680;    // lds: 2*6*63*4*64*8   = 1,548,288
    const size_t WPO_S8 = 4883968;    // lds: 8*8*63*4*64*8   = 8,257,536

    pack_x<<<23328, 256, 0, stream>>>(x, H);
    pack_w<<<(32768 + 255) / 256, 256, 0, stream>>>(Wf[0], wpb + WPO_S1, 7, 8, 24, 32, 32, 32768);
    pack_w<<<(96256 + 255) / 256, 256, 0, stream>>>(Wf[1], wpb + WPO_S2, 20, 24, 24, 32, 94, 96256);
    pack_w<<<(192512 + 255) / 256, 256, 0, stream>>>(Wf[2], wpb + WPO_S3, 20, 24, 56, 64, 94, 192512);
    pack_w<<<(770048 + 255) / 256, 256, 0, stream>>>(Wf[4], wpb + WPO_S5, 47, 48, 114, 64, 188, 770048);
    pack_w<<<(1728000 + 255) / 256, 256, 0, stream>>>(Wf[6], wpb + WPO_S7, 96, 96, 144, 48, 375, 1728000);
    pack_w_lds<<<(516096 + 255) / 256, 256, 0, stream>>>(Wf[3], wpb + WPO_S4, 47, 56, 64, 4, 516096);
    pack_w_lds<<<(1548288 + 255) / 256, 256, 0, stream>>>(Wf[5], wpb + WPO_S6, 96, 114, 64, 6, 1548288);
    pack_w_lds<<<(8257536 + 255) / 256, 256, 0, stream>>>(Wf[7], wpb + WPO_S8, 120, 512, 64, 8, 8257536);

    long rows;

    // stage 1 (ig): 64->34 s2, Cout 24, K=1000
    rows = 628864;
    conv_ig<8, 72, 34, 2, 24, 2, 32, 1000><<<dim3(2457, 1), 256, 0, stream>>>(H, wpb + WPO_S1, yb);
    bn_partial_cl<<<256, 256, 0, stream>>>(yb, part, rows, 24, 5);
    bn_finalize<<<1, 256, 0, stream>>>(part, stats, 24, 1.f / (float)rows);
    act_pad<24, 42, 34><<<111132, 256, 0, stream>>>(yb, stats, H, 24, 20, 6, 3);

    // stage 2 (ig, CONTROL): 34->38 s1, Cout 24, K=3000
    rows = 877952;
    conv_ig<24, 42, 38, 1, 24, 2, 94, 3000><<<dim3(3430, 1), 256, 0, stream>>>(H, wpb + WPO_S2, yb);
    bn_partial_cl<<<256, 256, 0, stream>>>(yb, part, rows, 24, 5);
    bn_finalize<<<1, 256, 0, stream>>>(part, stats, 24, 1.f / (float)rows);
    act_pad<24, 46, 38><<<146004, 256, 0, stream>>>(yb, stats, H, 24, 20, 6, 3);

    // stage 3 (ig): 38->21 s2, Cout 56, K=3000
    rows = 148176;
    conv_ig<24, 46, 21, 2, 56, 4, 94, 3000><<<dim3(579, 1), 256, 0, stream>>>(H, wpb + WPO_S3, yb);
    bn_partial_cl<<<256, 256, 0, stream>>>(yb, part, rows, 56, 6);
    bn_finalize<<<1, 256, 0, stream>>>(part, stats, 56, 1.f / (float)rows);
    act_pad<64, 29, 21><<<97556, 256, 0, stream>>>(yb, stats, H, 56, 47, 14, 6);   // pad 47->64ch

    // stage 4 (lds, BISECT): 21->25 s1, Cout 56, CH=64, tile (2,5,25)
    rows = 250000;
    conv_lds<4, 29, 25, 2, 5, 56, 4><<<dim3(1040, 1), 256, 0, stream>>>(H, wpb + WPO_S4, yb);
    bn_partial_cl<<<256, 256, 0, stream>>>(yb, part, rows, 56, 6);
    bn_finalize<<<1, 256, 0, stream>>>(part, stats, 56, 1.f / (float)rows);
    act_pad<48, 33, 25><<<107811, 256, 0, stream>>>(yb, stats, H, 56, 47, 14, 6);

    // stage 5 (ig): 25->15 s2, Cout 114, K=6000
    rows = 54000;
    conv_ig<48, 33, 15, 2, 114, 4, 188, 6000><<<dim3(211, 2), 256, 0, stream>>>(H, wpb + WPO_S5, yb);
    bn_partial_cl<<<256, 256, 0, stream>>>(yb, part, rows, 114, 7);
    bn_finalize<<<1, 256, 0, stream>>>(part, stats, 114, 1.f / (float)rows);
    act_pad<96, 23, 15><<<73002, 256, 0, stream>>>(yb, stats, H, 114, 96, 30, 12);

    // stage 6 (lds, BISECT): 15->19 s1, Cout 114, CH=96, tile (2,6,19)
    rows = 109744;
    conv_lds<6, 23, 19, 2, 6, 114, 4><<<dim3(640, 2), 256, 0, stream>>>(H, wpb + WPO_S6, yb);
    bn_partial_cl<<<256, 256, 0, stream>>>(yb, part, rows, 114, 7);
    bn_finalize<<<1, 256, 0, stream>>>(part, stats, 114, 1.f / (float)rows);
    act_pad<96, 27, 19><<<118098, 256, 0, stream>>>(yb, stats, H, 114, 96, 30, 12);

    // stage 7 (ig): 19->12 s2, Cout 144, K=12000
    rows = 27648;
    conv_ig<96, 27, 12, 2, 144, 3, 375, 12000><<<dim3(108, 3), 256, 0, stream>>>(H, wpb + WPO_S7, yb);
    bn_partial_cl<<<256, 256, 0, stream>>>(yb, part, rows, 144, 8);
    bn_finalize<<<1, 256, 0, stream>>>(part, stats, 144, 1.f / (float)rows);
    act_pad<128, 20, 12><<<64000, 256, 0, stream>>>(yb, stats, H, 144, 120, 32, 16); // pad 120->128ch

    // stage 8 (lds): 12->16 s1, Cout 512 as two 256-col halves
    rows = 65536;
    for (int h8 = 0; h8 < 2; ++h8) {
        conv_lds<8, 20, 16, 4, 4, 256, 4><<<dim3(256, 4), 256, 0, stream>>>(
            H, wpb + WPO_S8 + (size_t)h8 * 4128768, yb);
        bn_partial_cl<<<256, 256, 0, stream>>>(yb, part, rows, 256, 8);
        bn_finalize<<<1, 256, 0, stream>>>(part, stats, 256, 1.f / (float)rows);
        pool_partial<<<dim3(16, 64), 256, 0, stream>>>(yb, stats, pp);
        pool_final<<<16, 256, 0, stream>>>(pp, pooled + h8 * 256);
    }
    linear20<<<dim3(20, 16), 64, 0, stream>>>(pooled, linW, linb, out);
}